// Round 4
// baseline (2899.737 us; speedup 1.0000x reference)
//
#include <hip/hip_runtime.h>

// GraphDecoder (NRI) — round 4: runtime-dtype DIAGNOSTIC build.
// Single fused kernel, zero workspace. Detects fp32-vs-bf16 storage at
// runtime from rel_type sign bits (softmax > 0 => bf16 words never have
// bit15 set; f32 low-half words do). All loads sanitized (NaN/inf -> 0) so
// the verdict is always finite. Output store matches detected dtype.
// B=32, N=64, F=128, K=4, H=M=NH=256, E=4032.
// Edge structure: e = i*63 + jj, receiver i, sender j = jj + (jj>=i).

#define B_    32
#define N_    64
#define F_    128
#define K_    4
#define E_    4032
#define HROW  264

typedef unsigned short u16;

__device__ __forceinline__ float bf2f(u16 u) {
    unsigned v = ((unsigned)u) << 16;
    float f; __builtin_memcpy(&f, &v, 4); return f;
}
__device__ __forceinline__ u16 f2bf(float f) {
    unsigned u; __builtin_memcpy(&u, &f, 4);
    return (u16)((u + 0x7FFFu + ((u >> 16) & 1u)) >> 16);
}
__device__ __forceinline__ float san(float v) {
    return (v == v && v < 1e30f && v > -1e30f) ? v : 0.f;
}

template<bool F32>
__device__ __forceinline__ float ld(const void* p, int i) {
    if constexpr (F32) return san(((const float*)p)[i]);
    else               return san(bf2f(((const u16*)p)[i]));
}

template<bool F32>
__device__ void body(const void* x, const void* rel,
                     const void* W1, const void* b1,
                     const void* W2, const void* b2,
                     const void* Wo1, const void* bo1,
                     const void* Wo2, const void* bo2,
                     const void* Wo3, const void* bo3,
                     void* out,
                     u16* hS, float* rtS, float* aggS,
                     float* xS, float* p1S, float* p2S)
{
    const int tid = threadIdx.x;
    const int rt  = tid >> 5;          // 0..7 row-group (8 edge rows each)
    const int ct  = tid & 31;          // 0..31 col-group (8 cols each)
    const int bid = blockIdx.x;
    const int b   = bid >> 6;
    const int i   = bid & 63;          // receiver node

    aggS[tid] = 0.f;
    if (tid < 128) xS[tid] = ld<F32>(x, (b * N_ + i) * F_ + tid);
    {
        int row = tid >> 2, kk = tid & 3;
        float v = 0.f;
        if (row < 63) v = ld<F32>(rel, ((b * E_) + i * 63 + row) * K_ + kk);
        rtS[row * 4 + kk] = v;
    }

    int xjbase[8];
#pragma unroll
    for (int rr = 0; rr < 8; ++rr) {
        int row = rt * 8 + rr;
        int j = (row < i) ? row : row + 1;
        if (j > 63) j = 63;            // dummy row 63, masked by rtS=0
        xjbase[rr] = (b * N_ + j) * F_;
    }

    float aggAcc[8];
#pragma unroll
    for (int cc = 0; cc < 8; ++cc) aggAcc[cc] = 0.f;

    __syncthreads();

    for (int k = 0; k < K_; ++k) {
        __syncthreads();   // prior layer-2 hS reads done before overwrite

        // ---- layer 1: h = relu(pre @ W1[k] + b1[k]) ----
        float acc[8][8];
        {
            float bias[8];
#pragma unroll
            for (int cc = 0; cc < 8; ++cc) bias[cc] = ld<F32>(b1, k * 256 + ct * 8 + cc);
#pragma unroll
            for (int rr = 0; rr < 8; ++rr)
#pragma unroll
                for (int cc = 0; cc < 8; ++cc) acc[rr][cc] = bias[cc];
        }
        // receiver half (shared across all rows of this block)
        for (int f = 0; f < 128; ++f) {
            float w[8];
#pragma unroll
            for (int cc = 0; cc < 8; ++cc)
                w[cc] = ld<F32>(W1, k * 65536 + f * 256 + ct * 8 + cc);
            float pr = xS[f];
#pragma unroll
            for (int rr = 0; rr < 8; ++rr)
#pragma unroll
                for (int cc = 0; cc < 8; ++cc) acc[rr][cc] += pr * w[cc];
        }
        // sender half
        for (int f = 0; f < 128; ++f) {
            float w[8];
#pragma unroll
            for (int cc = 0; cc < 8; ++cc)
                w[cc] = ld<F32>(W1, k * 65536 + (128 + f) * 256 + ct * 8 + cc);
            float pr[8];
#pragma unroll
            for (int rr = 0; rr < 8; ++rr) pr[rr] = ld<F32>(x, xjbase[rr] + f);
#pragma unroll
            for (int rr = 0; rr < 8; ++rr)
#pragma unroll
                for (int cc = 0; cc < 8; ++cc) acc[rr][cc] += pr[rr] * w[cc];
        }
#pragma unroll
        for (int rr = 0; rr < 8; ++rr)
#pragma unroll
            for (int cc = 0; cc < 8; ++cc) {
                float v = acc[rr][cc];
                v = v > 0.f ? v : 0.f;
                hS[(rt * 8 + rr) * HROW + ct * 8 + cc] = f2bf(v);
            }
        __syncthreads();

        // ---- layer 2: msg = relu(h @ W2[k] + b2[k]); agg += rel_type * msg ----
        float acc2[8][8];
        {
            float bias[8];
#pragma unroll
            for (int cc = 0; cc < 8; ++cc) bias[cc] = ld<F32>(b2, k * 256 + ct * 8 + cc);
#pragma unroll
            for (int rr = 0; rr < 8; ++rr)
#pragma unroll
                for (int cc = 0; cc < 8; ++cc) acc2[rr][cc] = bias[cc];
        }
        for (int h = 0; h < 256; ++h) {
            float w[8];
#pragma unroll
            for (int cc = 0; cc < 8; ++cc)
                w[cc] = ld<F32>(W2, k * 65536 + h * 256 + ct * 8 + cc);
            float pr[8];
#pragma unroll
            for (int rr = 0; rr < 8; ++rr) pr[rr] = bf2f(hS[(rt * 8 + rr) * HROW + h]);
#pragma unroll
            for (int rr = 0; rr < 8; ++rr)
#pragma unroll
                for (int cc = 0; cc < 8; ++cc) acc2[rr][cc] += pr[rr] * w[cc];
        }
#pragma unroll
        for (int rr = 0; rr < 8; ++rr) {
            float rtw = rtS[(rt * 8 + rr) * 4 + k];
#pragma unroll
            for (int cc = 0; cc < 8; ++cc) {
                float v = acc2[rr][cc];
                v = v > 0.f ? v : 0.f;
                aggAcc[cc] += rtw * v;
            }
        }
    }

#pragma unroll
    for (int cc = 0; cc < 8; ++cc) atomicAdd(&aggS[ct * 8 + cc], aggAcc[cc]);
    __syncthreads();

    // ---- fused output MLP for node (b,i): aug = [xS, aggS] ----
    const int t = tid;
    {
        float acc = ld<F32>(bo1, t);
        for (int f = 0; f < 128; ++f) acc += xS[f]   * ld<F32>(Wo1, f * 256 + t);
        for (int f = 0; f < 256; ++f) acc += aggS[f] * ld<F32>(Wo1, (128 + f) * 256 + t);
        p1S[t] = acc > 0.f ? acc : 0.f;
    }
    __syncthreads();
    {
        float acc = ld<F32>(bo2, t);
        for (int h = 0; h < 256; ++h) acc += p1S[h] * ld<F32>(Wo2, h * 256 + t);
        p2S[t] = acc > 0.f ? acc : 0.f;
    }
    __syncthreads();
    if (t < 128) {
        float acc = ld<F32>(bo3, t);
        for (int h = 0; h < 256; ++h) acc += p2S[h] * ld<F32>(Wo3, h * 128 + t);
        float res = xS[t] + acc;
        int oidx = (b * N_ + i) * F_ + t;
        if constexpr (F32) ((float*)out)[oidx] = res;
        else               ((u16*)out)[oidx]   = f2bf(res);
    }
}

__global__ __launch_bounds__(256) void fused_kernel(
    const void* x, const void* rel,
    const void* W1, const void* b1, const void* W2, const void* b2,
    const void* Wo1, const void* bo1, const void* Wo2, const void* bo2,
    const void* Wo3, const void* bo3, void* out)
{
    __shared__ u16   hS[64 * HROW];
    __shared__ float rtS[64 * 4];
    __shared__ float aggS[256];
    __shared__ float xS[128];
    __shared__ float p1S[256];
    __shared__ float p2S[256];

    // Runtime dtype probe: rel_type is softmax output (>0). As bf16, no word
    // has bit15 set. As f32, low-half words are ~uniform -> bit15 hit certain.
    unsigned a = 0;
    const u16* r16 = (const u16*)rel;
    for (int w = 0; w < 64; ++w) a |= r16[w];
    const bool isF32 = (a & 0x8000u) != 0;

    if (isF32) body<true >(x, rel, W1, b1, W2, b2, Wo1, bo1, Wo2, bo2, Wo3, bo3,
                           out, hS, rtS, aggS, xS, p1S, p2S);
    else       body<false>(x, rel, W1, b1, W2, b2, Wo1, bo1, Wo2, bo2, Wo3, bo3,
                           out, hS, rtS, aggS, xS, p1S, p2S);
}

extern "C" void kernel_launch(void* const* d_in, const int* in_sizes, int n_in,
                              void* d_out, int out_size, void* d_ws, size_t ws_size,
                              hipStream_t stream) {
    fused_kernel<<<B_ * N_, 256, 0, stream>>>(
        d_in[0], d_in[1],            // inputs, rel_type (rel_rec/rel_send unused)
        d_in[4], d_in[5], d_in[6], d_in[7],
        d_in[8], d_in[9], d_in[10], d_in[11], d_in[12], d_in[13],
        d_out);
}

// Round 5
// 570.896 us; speedup vs baseline: 5.0793x; 5.0793x over previous
//
#include <hip/hip_runtime.h>

// GraphDecoder (NRI) — round 5: bf16 MFMA edge MLP + fused f32 output MLP.
// Inputs/outputs are fp32 (established in round 4). Prep kernel converts
// W1/W2 (transposed, padded) and x to bf16 in d_ws; main kernel does the
// 137-GFLOP edge MLP on matrix cores with fp32 accumulation.
// B=32, N=64, F=128, K=4, H=M=NH=256, E=4032.
// Edge e = i*63 + jj: receiver i, sender j = jj + (jj>=i).

#define B_    32
#define N_    64
#define F_    128
#define K_    4
#define E_    4032
#define WROW    264                  // padded row (u16 elems): 16B-aligned rows, <=2-way LDS bank aliasing
#define KSTRIDE (256 * WROW)         // 67584 u16 per edge-type weight matrix
#define CHUNK   (32 * WROW)          // 8448 u16 per 32-out-col chunk
#define WS_NEEDED (2u * K_ * KSTRIDE * 2u + (unsigned)(B_ * N_ * F_) * 2u)  // 1605632 B

typedef unsigned short u16;
typedef u16    u16x8  __attribute__((ext_vector_type(8)));
typedef __bf16 bf16x8 __attribute__((ext_vector_type(8)));
typedef float  f32x4  __attribute__((ext_vector_type(4)));

__device__ __forceinline__ u16 f2bf(float f) {
    unsigned u; __builtin_memcpy(&u, &f, 4);
    return (u16)((u + 0x7FFFu + ((u >> 16) & 1u)) >> 16);
}
__device__ __forceinline__ float bf2f(u16 u) {
    unsigned v = ((unsigned)u) << 16;
    float f; __builtin_memcpy(&f, &v, 4); return f;
}

// ---------------- prep: f32 -> bf16, weights transposed to [k][out][264] ----------------
__global__ __launch_bounds__(256) void prep_kernel(
    const float* __restrict__ W1, const float* __restrict__ W2,
    const float* __restrict__ x,
    u16* __restrict__ W1t, u16* __restrict__ W2t, u16* __restrict__ xb)
{
    unsigned gid = blockIdx.x * 256u + threadIdx.x;
    if (gid < 262144u) {                       // W1 [K,2F,H] -> W1t[k][h][f]
        unsigned k = gid >> 16, f = (gid >> 8) & 255u, h = gid & 255u;
        W1t[k * KSTRIDE + h * WROW + f] = f2bf(W1[gid]);
    } else if (gid < 524288u) {                // W2 [K,H,M] -> W2t[k][m][h]
        unsigned idx = gid - 262144u;
        unsigned k = idx >> 16, hh = (idx >> 8) & 255u, m = idx & 255u;
        W2t[k * KSTRIDE + m * WROW + hh] = f2bf(W2[idx]);
    } else {                                   // x -> bf16
        unsigned idx = gid - 524288u;
        xb[idx] = f2bf(x[idx]);
    }
}

// ---------------- fused edge-MLP (MFMA) + output MLP ----------------
// grid = B*N (one block per (b, receiver i)), 256 threads = 4 waves x 16 rows.
__global__ __launch_bounds__(256, 3) void edge_mfma_kernel(
    const u16* __restrict__ xb,        // [B,N,F] bf16
    const float* __restrict__ x,       // [B,N,F] f32 (residual)
    const float* __restrict__ rel,     // [B,E,K] f32
    const u16* __restrict__ W1t, const u16* __restrict__ W2t,
    const float* __restrict__ b1, const float* __restrict__ b2,
    const float* __restrict__ Wo1, const float* __restrict__ bo1,
    const float* __restrict__ Wo2, const float* __restrict__ bo2,
    const float* __restrict__ Wo3, const float* __restrict__ bo3,
    float* __restrict__ out)           // [B,N,F] f32
{
    __shared__ u16   ldsX[64 * WROW];  // pre_msg, then h, then (aliased) epilogue f32 buffers
    __shared__ u16   WtS[32 * WROW];   // weight chunk: 32 out-cols x 256 in (padded)
    __shared__ float rtS[256];         // rel_type scales [row][k]
    __shared__ float aggS[256];        // aggregated message for node (b,i)

    const int tid  = threadIdx.x;
    const int lane = tid & 63;
    const int w    = tid >> 6;         // wave 0..3 -> rows w*16..w*16+15
    const int bid  = blockIdx.x;
    const int b    = bid >> 6;
    const int i    = bid & 63;         // receiver node
    const int quad = lane >> 4;
    const int mloc = lane & 15;

    aggS[tid] = 0.f;
    {
        int row = tid >> 2, kk = tid & 3;
        rtS[tid] = (row < 63) ? rel[((b * E_) + i * 63 + row) * K_ + kk] : 0.f;
    }
    // stage pre_msg rows (bf16): cols 0..127 receiver, 128..255 sender
    for (int it = 0; it < 8; ++it) {
        int chunk = it * 256 + tid;
        int row = chunk >> 5, c = chunk & 31;
        int j = (row < i) ? row : row + 1;
        if (j > 63) j = 0;             // dummy row 63, masked by rtS=0
        const u16* src = (c < 16) ? &xb[(b * N_ + i) * F_ + c * 8]
                                  : &xb[(b * N_ + j) * F_ + (c - 16) * 8];
        *(u16x8*)&ldsX[row * WROW + c * 8] = *(const u16x8*)src;
    }
    __syncthreads();

    const int aoff = (w * 16 + mloc) * WROW + quad * 8;
    bf16x8 aF1[8];                     // layer-1 A fragments, live across all k
#pragma unroll
    for (int ks = 0; ks < 8; ++ks) aF1[ks] = *(const bf16x8*)&ldsX[aoff + ks * 32];

    float amsg[16];
#pragma unroll
    for (int g = 0; g < 16; ++g) amsg[g] = 0.f;

    for (int k = 0; k < K_; ++k) {
        float rts[4];
#pragma unroll
        for (int r = 0; r < 4; ++r) rts[r] = rtS[(w * 16 + quad * 4 + r) * 4 + k];

        // ---- layer 1: h = relu(pre @ W1[k] + b1[k]) -> ldsX (bf16) ----
        for (int c = 0; c < 8; ++c) {
            __syncthreads();           // prior WtS readers done
            {
                const u16* src = W1t + k * KSTRIDE + c * CHUNK;
                for (int t2 = tid; t2 < 1056; t2 += 256)
                    *(u16x8*)&WtS[t2 * 8] = *(const u16x8*)&src[t2 * 8];
            }
            __syncthreads();
#pragma unroll
            for (int nt = 0; nt < 2; ++nt) {
                f32x4 acc = (f32x4){0.f, 0.f, 0.f, 0.f};
                const int boff = (nt * 16 + mloc) * WROW + quad * 8;
#pragma unroll
                for (int ks = 0; ks < 8; ++ks)
                    acc = __builtin_amdgcn_mfma_f32_16x16x32_bf16(
                        aF1[ks], *(const bf16x8*)&WtS[boff + ks * 32], acc, 0, 0, 0);
                const int n = c * 32 + nt * 16 + mloc;
                const float bv = b1[k * 256 + n];
#pragma unroll
                for (int r = 0; r < 4; ++r) {
                    float v = acc[r] + bv;
                    v = v > 0.f ? v : 0.f;
                    ldsX[(w * 16 + quad * 4 + r) * WROW + n] = f2bf(v);
                }
            }
        }
        __syncthreads();               // h complete across all waves

        bf16x8 aF2[8];
#pragma unroll
        for (int ks = 0; ks < 8; ++ks) aF2[ks] = *(const bf16x8*)&ldsX[aoff + ks * 32];

        // ---- layer 2: msg = relu(h @ W2[k] + b2[k]); amsg += rel_type * msg ----
        for (int c = 0; c < 8; ++c) {
            __syncthreads();
            {
                const u16* src = W2t + k * KSTRIDE + c * CHUNK;
                for (int t2 = tid; t2 < 1056; t2 += 256)
                    *(u16x8*)&WtS[t2 * 8] = *(const u16x8*)&src[t2 * 8];
            }
            __syncthreads();
#pragma unroll
            for (int nt = 0; nt < 2; ++nt) {
                f32x4 acc = (f32x4){0.f, 0.f, 0.f, 0.f};
                const int boff = (nt * 16 + mloc) * WROW + quad * 8;
#pragma unroll
                for (int ks = 0; ks < 8; ++ks)
                    acc = __builtin_amdgcn_mfma_f32_16x16x32_bf16(
                        aF2[ks], *(const bf16x8*)&WtS[boff + ks * 32], acc, 0, 0, 0);
                const int n = c * 32 + nt * 16 + mloc;
                const float bv = b2[k * 256 + n];
                float s = 0.f;
#pragma unroll
                for (int r = 0; r < 4; ++r) {
                    float v = acc[r] + bv;
                    v = v > 0.f ? v : 0.f;
                    s += rts[r] * v;
                }
                amsg[c * 2 + nt] += s;
            }
        }
    }

    // reduce over 64 edge rows: amsg[g] holds 4-row partial for col g*16+mloc
#pragma unroll
    for (int g = 0; g < 16; ++g) {
        float s = amsg[g];
        s += __shfl_xor(s, 16);
        s += __shfl_xor(s, 32);
        if (quad == 0) atomicAdd(&aggS[g * 16 + mloc], s);
    }
    __syncthreads();

    // ---- fused output MLP (f32 VALU): aug = [x(b,i,:), aggS] ----
    float* xS  = (float*)ldsX;         // ldsX dead now; alias epilogue buffers
    float* p1S = xS + 128;
    float* p2S = p1S + 256;
    if (tid < 128) xS[tid] = x[(b * N_ + i) * F_ + tid];
    __syncthreads();
    const int t = tid;
    {
        float acc = bo1[t];
        for (int f = 0; f < 128; ++f) acc += xS[f]   * Wo1[f * 256 + t];
        for (int f = 0; f < 256; ++f) acc += aggS[f] * Wo1[(128 + f) * 256 + t];
        p1S[t] = acc > 0.f ? acc : 0.f;
    }
    __syncthreads();
    {
        float acc = bo2[t];
        for (int h = 0; h < 256; ++h) acc += p1S[h] * Wo2[h * 256 + t];
        p2S[t] = acc > 0.f ? acc : 0.f;
    }
    __syncthreads();
    if (t < 128) {
        float acc = bo3[t];
        for (int h = 0; h < 256; ++h) acc += p2S[h] * Wo3[h * 128 + t];
        out[(b * N_ + i) * F_ + t] = xS[t] + acc;
    }
}

// ---------------- fallback (round-4 f32 VALU path, used only if ws too small) ----------------
#define HROW 264
__global__ __launch_bounds__(256) void fallback_kernel(
    const float* __restrict__ x, const float* __restrict__ rel,
    const float* __restrict__ W1, const float* __restrict__ b1,
    const float* __restrict__ W2, const float* __restrict__ b2,
    const float* __restrict__ Wo1, const float* __restrict__ bo1,
    const float* __restrict__ Wo2, const float* __restrict__ bo2,
    const float* __restrict__ Wo3, const float* __restrict__ bo3,
    float* __restrict__ out)
{
    __shared__ u16   hS[64 * HROW];
    __shared__ float rtS[256];
    __shared__ float aggS[256];
    __shared__ float xS[128];
    __shared__ float p1S[256];
    __shared__ float p2S[256];

    const int tid = threadIdx.x;
    const int rt = tid >> 5, ct = tid & 31;
    const int bid = blockIdx.x, b = bid >> 6, i = bid & 63;

    aggS[tid] = 0.f;
    if (tid < 128) xS[tid] = x[(b * N_ + i) * F_ + tid];
    {
        int row = tid >> 2, kk = tid & 3;
        rtS[tid] = (row < 63) ? rel[((b * E_) + i * 63 + row) * K_ + kk] : 0.f;
    }
    int xjbase[8];
#pragma unroll
    for (int rr = 0; rr < 8; ++rr) {
        int row = rt * 8 + rr;
        int j = (row < i) ? row : row + 1;
        if (j > 63) j = 63;
        xjbase[rr] = (b * N_ + j) * F_;
    }
    float aggAcc[8];
#pragma unroll
    for (int cc = 0; cc < 8; ++cc) aggAcc[cc] = 0.f;
    __syncthreads();

    for (int k = 0; k < K_; ++k) {
        __syncthreads();
        float acc[8][8];
#pragma unroll
        for (int rr = 0; rr < 8; ++rr)
#pragma unroll
            for (int cc = 0; cc < 8; ++cc) acc[rr][cc] = b1[k * 256 + ct * 8 + cc];
        for (int f = 0; f < 128; ++f) {
            float wv[8];
#pragma unroll
            for (int cc = 0; cc < 8; ++cc) wv[cc] = W1[k * 65536 + f * 256 + ct * 8 + cc];
            float pr = xS[f];
#pragma unroll
            for (int rr = 0; rr < 8; ++rr)
#pragma unroll
                for (int cc = 0; cc < 8; ++cc) acc[rr][cc] += pr * wv[cc];
        }
        for (int f = 0; f < 128; ++f) {
            float wv[8];
#pragma unroll
            for (int cc = 0; cc < 8; ++cc) wv[cc] = W1[k * 65536 + (128 + f) * 256 + ct * 8 + cc];
            float pr[8];
#pragma unroll
            for (int rr = 0; rr < 8; ++rr) pr[rr] = x[xjbase[rr] + f];
#pragma unroll
            for (int rr = 0; rr < 8; ++rr)
#pragma unroll
                for (int cc = 0; cc < 8; ++cc) acc[rr][cc] += pr[rr] * wv[cc];
        }
#pragma unroll
        for (int rr = 0; rr < 8; ++rr)
#pragma unroll
            for (int cc = 0; cc < 8; ++cc) {
                float v = acc[rr][cc]; v = v > 0.f ? v : 0.f;
                hS[(rt * 8 + rr) * HROW + ct * 8 + cc] = f2bf(v);
            }
        __syncthreads();
        float acc2[8][8];
#pragma unroll
        for (int rr = 0; rr < 8; ++rr)
#pragma unroll
            for (int cc = 0; cc < 8; ++cc) acc2[rr][cc] = b2[k * 256 + ct * 8 + cc];
        for (int h = 0; h < 256; ++h) {
            float wv[8];
#pragma unroll
            for (int cc = 0; cc < 8; ++cc) wv[cc] = W2[k * 65536 + h * 256 + ct * 8 + cc];
            float pr[8];
#pragma unroll
            for (int rr = 0; rr < 8; ++rr) pr[rr] = bf2f(hS[(rt * 8 + rr) * HROW + h]);
#pragma unroll
            for (int rr = 0; rr < 8; ++rr)
#pragma unroll
                for (int cc = 0; cc < 8; ++cc) acc2[rr][cc] += pr[rr] * wv[cc];
        }
#pragma unroll
        for (int rr = 0; rr < 8; ++rr) {
            float rtw = rtS[(rt * 8 + rr) * 4 + k];
#pragma unroll
            for (int cc = 0; cc < 8; ++cc) {
                float v = acc2[rr][cc]; v = v > 0.f ? v : 0.f;
                aggAcc[cc] += rtw * v;
            }
        }
    }
#pragma unroll
    for (int cc = 0; cc < 8; ++cc) atomicAdd(&aggS[ct * 8 + cc], aggAcc[cc]);
    __syncthreads();
    const int t = tid;
    {
        float acc = bo1[t];
        for (int f = 0; f < 128; ++f) acc += xS[f] * Wo1[f * 256 + t];
        for (int f = 0; f < 256; ++f) acc += aggS[f] * Wo1[(128 + f) * 256 + t];
        p1S[t] = acc > 0.f ? acc : 0.f;
    }
    __syncthreads();
    {
        float acc = bo2[t];
        for (int h = 0; h < 256; ++h) acc += p1S[h] * Wo2[h * 256 + t];
        p2S[t] = acc > 0.f ? acc : 0.f;
    }
    __syncthreads();
    if (t < 128) {
        float acc = bo3[t];
        for (int h = 0; h < 256; ++h) acc += p2S[h] * Wo3[h * 128 + t];
        out[(b * N_ + i) * F_ + t] = xS[t] + acc;
    }
}

extern "C" void kernel_launch(void* const* d_in, const int* in_sizes, int n_in,
                              void* d_out, int out_size, void* d_ws, size_t ws_size,
                              hipStream_t stream) {
    const float* x    = (const float*)d_in[0];
    const float* rel  = (const float*)d_in[1];
    const float* W1   = (const float*)d_in[4];
    const float* b1   = (const float*)d_in[5];
    const float* W2   = (const float*)d_in[6];
    const float* b2   = (const float*)d_in[7];
    const float* Wo1  = (const float*)d_in[8];
    const float* bo1  = (const float*)d_in[9];
    const float* Wo2  = (const float*)d_in[10];
    const float* bo2  = (const float*)d_in[11];
    const float* Wo3  = (const float*)d_in[12];
    const float* bo3  = (const float*)d_in[13];
    float* out = (float*)d_out;

    if (ws_size >= (size_t)WS_NEEDED) {
        u16* W1t = (u16*)d_ws;
        u16* W2t = W1t + K_ * KSTRIDE;
        u16* xb  = W2t + K_ * KSTRIDE;
        prep_kernel<<<3072, 256, 0, stream>>>(W1, W2, x, W1t, W2t, xb);
        edge_mfma_kernel<<<B_ * N_, 256, 0, stream>>>(
            xb, x, rel, W1t, W2t, b1, b2, Wo1, bo1, Wo2, bo2, Wo3, bo3, out);
    } else {
        fallback_kernel<<<B_ * N_, 256, 0, stream>>>(
            x, rel, W1, b1, W2, b2, Wo1, bo1, Wo2, bo2, Wo3, bo3, out);
    }
}

// Round 6
// 349.329 us; speedup vs baseline: 8.3009x; 1.6343x over previous
//
#include <hip/hip_runtime.h>

// GraphDecoder (NRI) — round 6: factorized layer-1 (R/S tables) + dbuf MFMA layer-2.
// h = relu(R[b,recv] + S[b,send]),  R = x@W1[:, :128,:]+b1, S = x@W1[:,128:,:]
// kills layer-1 edge GEMM (68 GFLOP) and its weight streaming.
// B=32, N=64, F=128, K=4, H=M=NH=256, E=4032.  Edge e=i*63+jj: recv i, send j=jj+(jj>=i).

#define B_    32
#define N_    64
#define F_    128
#define K_    4
#define E_    4032
#define WROW    264                   // padded row (u16): 16B-aligned, even LDS bank spread
#define KSTRIDE (256 * WROW)
#define CHUNK   (32 * WROW)           // 8448 u16 = 16896 B per 32-out-col chunk
#define AROW    136                   // kernel-A LDS pad (128+8)

#define WS_W1T  0u
#define WS_W2T  540672u
#define WS_XB   1081344u
#define WS_R    1605632u
#define WS_S    5799936u
#define WS_NEW  9994240u
#define WS_OLD  1605632u

typedef unsigned short u16;
typedef u16    u16x8  __attribute__((ext_vector_type(8)));
typedef __bf16 bf16x8 __attribute__((ext_vector_type(8)));
typedef float  f32x4  __attribute__((ext_vector_type(4)));

__device__ __forceinline__ u16 f2bf(float f) {
    unsigned u; __builtin_memcpy(&u, &f, 4);
    return (u16)((u + 0x7FFFu + ((u >> 16) & 1u)) >> 16);
}
__device__ __forceinline__ float bf2f(u16 u) {
    unsigned v = ((unsigned)u) << 16;
    float f; __builtin_memcpy(&f, &v, 4); return f;
}

// ---------------- prep: f32 -> bf16, weights transposed to [k][out][WROW] ----------------
__global__ __launch_bounds__(256) void prep_kernel(
    const float* __restrict__ W1, const float* __restrict__ W2,
    const float* __restrict__ x,
    u16* __restrict__ W1t, u16* __restrict__ W2t, u16* __restrict__ xb)
{
    unsigned gid = blockIdx.x * 256u + threadIdx.x;
    if (gid < 262144u) {                       // W1 [K,2F,H] -> W1t[k][h][f]
        unsigned k = gid >> 16, f = (gid >> 8) & 255u, h = gid & 255u;
        W1t[k * KSTRIDE + h * WROW + f] = f2bf(W1[gid]);
    } else if (gid < 524288u) {                // W2 [K,H,M] -> W2t[k][m][h]
        unsigned idx = gid - 262144u;
        unsigned k = idx >> 16, hh = (idx >> 8) & 255u, m = idx & 255u;
        W2t[k * KSTRIDE + m * WROW + hh] = f2bf(W2[idx]);
    } else {                                   // x -> bf16
        unsigned idx = gid - 524288u;
        xb[idx] = f2bf(x[idx]);
    }
}

// ---------------- kernel A: R/S tables via MFMA ----------------
// grid = (k, half, b) = 4*2*32 = 256 blocks. Block: 64 node-rows x 256 cols, K=128.
// R[b,i,k,n] = sum_f x[b,i,f]*W1[k][f][n] + b1[k][n]   (half=0)
// S[b,j,k,n] = sum_f x[b,j,f]*W1[k][128+f][n]          (half=1)
__global__ __launch_bounds__(256) void rs_kernel(
    const u16* __restrict__ xb, const u16* __restrict__ W1t,
    const float* __restrict__ b1,
    u16* __restrict__ R, u16* __restrict__ S)
{
    __shared__ u16 ldsA[64 * AROW];
    __shared__ u16 WtSa[32 * AROW];

    const int tid  = threadIdx.x;
    const int lane = tid & 63;
    const int w    = tid >> 6;
    const int quad = lane >> 4;
    const int mloc = lane & 15;
    const int bx   = blockIdx.x;
    const int k    = bx >> 6;
    const int half = (bx >> 5) & 1;
    const int b    = bx & 31;

    // stage x rows for batch b
    for (int it = 0; it < 4; ++it) {
        int idx = it * 256 + tid;
        int row = idx >> 4, g = idx & 15;
        *(u16x8*)&ldsA[row * AROW + g * 8] = *(const u16x8*)&xb[(b * 64 + row) * 128 + g * 8];
    }
    __syncthreads();

    bf16x8 aF[4];
#pragma unroll
    for (int ks = 0; ks < 4; ++ks)
        aF[ks] = *(const bf16x8*)&ldsA[(w * 16 + mloc) * AROW + quad * 8 + ks * 32];

    u16* dst = half ? S : R;

    for (int c = 0; c < 8; ++c) {
        __syncthreads();
        for (int it = 0; it < 2; ++it) {
            int idx = it * 256 + tid;
            int nn = idx >> 4, g = idx & 15;
            *(u16x8*)&WtSa[nn * AROW + g * 8] =
                *(const u16x8*)&W1t[k * KSTRIDE + (c * 32 + nn) * WROW + half * 128 + g * 8];
        }
        __syncthreads();
#pragma unroll
        for (int nt = 0; nt < 2; ++nt) {
            f32x4 acc = (f32x4){0.f, 0.f, 0.f, 0.f};
            const int boff = (nt * 16 + mloc) * AROW + quad * 8;
#pragma unroll
            for (int ks = 0; ks < 4; ++ks)
                acc = __builtin_amdgcn_mfma_f32_16x16x32_bf16(
                    aF[ks], *(const bf16x8*)&WtSa[boff + ks * 32], acc, 0, 0, 0);
            const int n = c * 32 + nt * 16 + mloc;
            const float bias = half ? 0.f : b1[k * 256 + n];
#pragma unroll
            for (int r = 0; r < 4; ++r) {
                int row = w * 16 + quad * 4 + r;
                dst[((k * 2048 + b * 64 + row) << 8) + n] = f2bf(acc[r] + bias);
            }
        }
    }
}

// ---------------- kernel B: layer-2 MFMA + aggregate + fused output MLP ----------------
// grid = B*N (one block per (b, receiver i)), 256 threads = 4 waves x 16 rows.
__global__ __launch_bounds__(256, 2) void edge2_kernel(
    const u16* __restrict__ R, const u16* __restrict__ S,
    const float* __restrict__ x, const float* __restrict__ rel,
    const u16* __restrict__ W2t, const float* __restrict__ b2,
    const float* __restrict__ Wo1, const float* __restrict__ bo1,
    const float* __restrict__ Wo2, const float* __restrict__ bo2,
    const float* __restrict__ Wo3, const float* __restrict__ bo3,
    float* __restrict__ out)
{
    __shared__ u16   ldsH[64 * WROW];     // H tile (bf16); aliased f32 epilogue buffers
    __shared__ u16   WtS[2 * CHUNK];      // double-buffered weight chunk
    __shared__ float rtS[256];
    __shared__ float aggS[256];

    const int tid  = threadIdx.x;
    const int lane = tid & 63;
    const int w    = tid >> 6;
    const int quad = lane >> 4;
    const int mloc = lane & 15;
    const int bid  = blockIdx.x;
    const int b    = bid >> 6;
    const int i    = bid & 63;

    aggS[tid] = 0.f;
    {
        int row = tid >> 2, kk = tid & 3;
        rtS[tid] = (row < 63) ? rel[((b * E_) + i * 63 + row) * K_ + kk] : 0.f;
    }

    const int cg = tid & 31;              // col-group for H build
    const int rg = tid >> 5;              // row-group (8 rows apart)
    const int aoff = (w * 16 + mloc) * WROW + quad * 8;

    float amsg[16];
#pragma unroll
    for (int g = 0; g < 16; ++g) amsg[g] = 0.f;

    for (int k = 0; k < K_; ++k) {
        __syncthreads();                  // ldsH + WtS buf0 free (prior k done)

        // ---- preload chunk 0 into registers ----
        u16x8 wreg[5];
        {
            const u16* src = W2t + k * KSTRIDE;
#pragma unroll
            for (int it = 0; it < 5; ++it) {
                int idx = it * 256 + tid;
                if (idx < 1056) wreg[it] = *(const u16x8*)&src[idx * 8];
            }
        }

        // ---- build H tile: H[row] = relu(R_i + S_j), bf16 ----
        {
            float Rv[8];
            {
                u16x8 t = *(const u16x8*)&R[((k * 2048 + b * 64 + i) << 8) + cg * 8];
#pragma unroll
                for (int e = 0; e < 8; ++e) Rv[e] = bf2f(t[e]);
            }
#pragma unroll
            for (int it = 0; it < 8; ++it) {
                int row = it * 8 + rg;
                int j = (row < i) ? row : row + 1;
                if (j > 63) j = 63;       // dummy row 63, masked by rtS=0
                u16x8 t = *(const u16x8*)&S[((k * 2048 + b * 64 + j) << 8) + cg * 8];
                u16x8 o;
#pragma unroll
                for (int e = 0; e < 8; ++e) {
                    float v = Rv[e] + bf2f(t[e]);
                    o[e] = f2bf(v > 0.f ? v : 0.f);
                }
                *(u16x8*)&ldsH[row * WROW + cg * 8] = o;
            }
        }
        // store chunk 0 regs -> buf0
#pragma unroll
        for (int it = 0; it < 5; ++it) {
            int idx = it * 256 + tid;
            if (idx < 1056) *(u16x8*)&WtS[idx * 8] = wreg[it];
        }

        float rts[4];
#pragma unroll
        for (int r = 0; r < 4; ++r) rts[r] = rtS[(w * 16 + quad * 4 + r) * 4 + k];

        bf16x8 aF2[8];
        for (int c = 0; c < 8; ++c) {
            __syncthreads();              // H + buf[c&1] visible; prior compute done
            if (c == 0) {
#pragma unroll
                for (int ks = 0; ks < 8; ++ks)
                    aF2[ks] = *(const bf16x8*)&ldsH[aoff + ks * 32];
            }
            // pipeline: load chunk c+1 into regs
            if (c < 7) {
                const u16* src = W2t + k * KSTRIDE + (c + 1) * CHUNK;
#pragma unroll
                for (int it = 0; it < 5; ++it) {
                    int idx = it * 256 + tid;
                    if (idx < 1056) wreg[it] = *(const u16x8*)&src[idx * 8];
                }
            }
            // compute chunk c
            const u16* buf = WtS + (c & 1) * CHUNK;
#pragma unroll
            for (int nt = 0; nt < 2; ++nt) {
                f32x4 acc = (f32x4){0.f, 0.f, 0.f, 0.f};
                const int boff = (nt * 16 + mloc) * WROW + quad * 8;
#pragma unroll
                for (int ks = 0; ks < 8; ++ks)
                    acc = __builtin_amdgcn_mfma_f32_16x16x32_bf16(
                        aF2[ks], *(const bf16x8*)&buf[boff + ks * 32], acc, 0, 0, 0);
                const int n = c * 32 + nt * 16 + mloc;
                const float bv = b2[k * 256 + n];
                float s = 0.f;
#pragma unroll
                for (int r = 0; r < 4; ++r) {
                    float v = acc[r] + bv;
                    v = v > 0.f ? v : 0.f;
                    s += rts[r] * v;
                }
                amsg[c * 2 + nt] += s;
            }
            // store chunk c+1 regs -> buf[(c+1)&1]
            if (c < 7) {
                u16* dbuf = WtS + ((c + 1) & 1) * CHUNK;
#pragma unroll
                for (int it = 0; it < 5; ++it) {
                    int idx = it * 256 + tid;
                    if (idx < 1056) *(u16x8*)&dbuf[idx * 8] = wreg[it];
                }
            }
        }
    }

    // reduce over 64 edge rows
#pragma unroll
    for (int g = 0; g < 16; ++g) {
        float s = amsg[g];
        s += __shfl_xor(s, 16);
        s += __shfl_xor(s, 32);
        if (quad == 0) atomicAdd(&aggS[g * 16 + mloc], s);
    }
    __syncthreads();

    // ---- fused output MLP: aug = [x(b,i,:), aggS] ----
    float* xS  = (float*)ldsH;
    float* p1S = xS + 128;
    float* p2S = p1S + 256;
    if (tid < 128) xS[tid] = x[(b * N_ + i) * F_ + tid];
    __syncthreads();
    const int t = tid;
    {
        float acc = bo1[t];
        for (int f = 0; f < 128; ++f) acc += xS[f]   * Wo1[f * 256 + t];
        for (int f = 0; f < 256; ++f) acc += aggS[f] * Wo1[(128 + f) * 256 + t];
        p1S[t] = acc > 0.f ? acc : 0.f;
    }
    __syncthreads();
    {
        float acc = bo2[t];
        for (int h = 0; h < 256; ++h) acc += p1S[h] * Wo2[h * 256 + t];
        p2S[t] = acc > 0.f ? acc : 0.f;
    }
    __syncthreads();
    if (t < 128) {
        float acc = bo3[t];
        for (int h = 0; h < 256; ++h) acc += p2S[h] * Wo3[h * 128 + t];
        out[(b * N_ + i) * F_ + t] = xS[t] + acc;
    }
}

// ---------------- round-5 proven path (fallback if ws too small) ----------------
__global__ __launch_bounds__(256, 3) void edge_mfma_kernel(
    const u16* __restrict__ xb, const float* __restrict__ x,
    const float* __restrict__ rel,
    const u16* __restrict__ W1t, const u16* __restrict__ W2t,
    const float* __restrict__ b1, const float* __restrict__ b2,
    const float* __restrict__ Wo1, const float* __restrict__ bo1,
    const float* __restrict__ Wo2, const float* __restrict__ bo2,
    const float* __restrict__ Wo3, const float* __restrict__ bo3,
    float* __restrict__ out)
{
    __shared__ u16   ldsX[64 * WROW];
    __shared__ u16   WtS[CHUNK];
    __shared__ float rtS[256];
    __shared__ float aggS[256];

    const int tid  = threadIdx.x;
    const int lane = tid & 63;
    const int w    = tid >> 6;
    const int bid  = blockIdx.x;
    const int b    = bid >> 6;
    const int i    = bid & 63;
    const int quad = lane >> 4;
    const int mloc = lane & 15;

    aggS[tid] = 0.f;
    {
        int row = tid >> 2, kk = tid & 3;
        rtS[tid] = (row < 63) ? rel[((b * E_) + i * 63 + row) * K_ + kk] : 0.f;
    }
    for (int it = 0; it < 8; ++it) {
        int chunk = it * 256 + tid;
        int row = chunk >> 5, c = chunk & 31;
        int j = (row < i) ? row : row + 1;
        if (j > 63) j = 0;
        const u16* src = (c < 16) ? &xb[(b * N_ + i) * F_ + c * 8]
                                  : &xb[(b * N_ + j) * F_ + (c - 16) * 8];
        *(u16x8*)&ldsX[row * WROW + c * 8] = *(const u16x8*)src;
    }
    __syncthreads();

    const int aoff = (w * 16 + mloc) * WROW + quad * 8;
    bf16x8 aF1[8];
#pragma unroll
    for (int ks = 0; ks < 8; ++ks) aF1[ks] = *(const bf16x8*)&ldsX[aoff + ks * 32];

    float amsg[16];
#pragma unroll
    for (int g = 0; g < 16; ++g) amsg[g] = 0.f;

    for (int k = 0; k < K_; ++k) {
        float rts[4];
#pragma unroll
        for (int r = 0; r < 4; ++r) rts[r] = rtS[(w * 16 + quad * 4 + r) * 4 + k];
        for (int c = 0; c < 8; ++c) {
            __syncthreads();
            {
                const u16* src = W1t + k * KSTRIDE + c * CHUNK;
                for (int t2 = tid; t2 < 1056; t2 += 256)
                    *(u16x8*)&WtS[t2 * 8] = *(const u16x8*)&src[t2 * 8];
            }
            __syncthreads();
#pragma unroll
            for (int nt = 0; nt < 2; ++nt) {
                f32x4 acc = (f32x4){0.f, 0.f, 0.f, 0.f};
                const int boff = (nt * 16 + mloc) * WROW + quad * 8;
#pragma unroll
                for (int ks = 0; ks < 8; ++ks)
                    acc = __builtin_amdgcn_mfma_f32_16x16x32_bf16(
                        aF1[ks], *(const bf16x8*)&WtS[boff + ks * 32], acc, 0, 0, 0);
                const int n = c * 32 + nt * 16 + mloc;
                const float bv = b1[k * 256 + n];
#pragma unroll
                for (int r = 0; r < 4; ++r) {
                    float v = acc[r] + bv;
                    v = v > 0.f ? v : 0.f;
                    ldsX[(w * 16 + quad * 4 + r) * WROW + n] = f2bf(v);
                }
            }
        }
        __syncthreads();
        bf16x8 aF2[8];
#pragma unroll
        for (int ks = 0; ks < 8; ++ks) aF2[ks] = *(const bf16x8*)&ldsX[aoff + ks * 32];
        for (int c = 0; c < 8; ++c) {
            __syncthreads();
            {
                const u16* src = W2t + k * KSTRIDE + c * CHUNK;
                for (int t2 = tid; t2 < 1056; t2 += 256)
                    *(u16x8*)&WtS[t2 * 8] = *(const u16x8*)&src[t2 * 8];
            }
            __syncthreads();
#pragma unroll
            for (int nt = 0; nt < 2; ++nt) {
                f32x4 acc = (f32x4){0.f, 0.f, 0.f, 0.f};
                const int boff = (nt * 16 + mloc) * WROW + quad * 8;
#pragma unroll
                for (int ks = 0; ks < 8; ++ks)
                    acc = __builtin_amdgcn_mfma_f32_16x16x32_bf16(
                        aF2[ks], *(const bf16x8*)&WtS[boff + ks * 32], acc, 0, 0, 0);
                const int n = c * 32 + nt * 16 + mloc;
                const float bv = b2[k * 256 + n];
                float s = 0.f;
#pragma unroll
                for (int r = 0; r < 4; ++r) {
                    float v = acc[r] + bv;
                    v = v > 0.f ? v : 0.f;
                    s += rts[r] * v;
                }
                amsg[c * 2 + nt] += s;
            }
        }
    }
#pragma unroll
    for (int g = 0; g < 16; ++g) {
        float s = amsg[g];
        s += __shfl_xor(s, 16);
        s += __shfl_xor(s, 32);
        if (quad == 0) atomicAdd(&aggS[g * 16 + mloc], s);
    }
    __syncthreads();
    float* xS  = (float*)ldsX;
    float* p1S = xS + 128;
    float* p2S = p1S + 256;
    if (tid < 128) xS[tid] = x[(b * N_ + i) * F_ + tid];
    __syncthreads();
    const int t = tid;
    {
        float acc = bo1[t];
        for (int f = 0; f < 128; ++f) acc += xS[f]   * Wo1[f * 256 + t];
        for (int f = 0; f < 256; ++f) acc += aggS[f] * Wo1[(128 + f) * 256 + t];
        p1S[t] = acc > 0.f ? acc : 0.f;
    }
    __syncthreads();
    {
        float acc = bo2[t];
        for (int h = 0; h < 256; ++h) acc += p1S[h] * Wo2[h * 256 + t];
        p2S[t] = acc > 0.f ? acc : 0.f;
    }
    __syncthreads();
    if (t < 128) {
        float acc = bo3[t];
        for (int h = 0; h < 256; ++h) acc += p2S[h] * Wo3[h * 128 + t];
        out[(b * N_ + i) * F_ + t] = xS[t] + acc;
    }
}

extern "C" void kernel_launch(void* const* d_in, const int* in_sizes, int n_in,
                              void* d_out, int out_size, void* d_ws, size_t ws_size,
                              hipStream_t stream) {
    const float* x    = (const float*)d_in[0];
    const float* rel  = (const float*)d_in[1];
    const float* W1   = (const float*)d_in[4];
    const float* b1   = (const float*)d_in[5];
    const float* W2   = (const float*)d_in[6];
    const float* b2   = (const float*)d_in[7];
    const float* Wo1  = (const float*)d_in[8];
    const float* bo1  = (const float*)d_in[9];
    const float* Wo2  = (const float*)d_in[10];
    const float* bo2  = (const float*)d_in[11];
    const float* Wo3  = (const float*)d_in[12];
    const float* bo3  = (const float*)d_in[13];
    float* out = (float*)d_out;

    char* ws = (char*)d_ws;
    u16* W1t = (u16*)(ws + WS_W1T);
    u16* W2t = (u16*)(ws + WS_W2T);
    u16* xb  = (u16*)(ws + WS_XB);

    prep_kernel<<<3072, 256, 0, stream>>>(W1, W2, x, W1t, W2t, xb);

    if (ws_size >= (size_t)WS_NEW) {
        u16* R = (u16*)(ws + WS_R);
        u16* S = (u16*)(ws + WS_S);
        rs_kernel<<<256, 256, 0, stream>>>(xb, W1t, b1, R, S);
        edge2_kernel<<<B_ * N_, 256, 0, stream>>>(
            R, S, x, rel, W2t, b2, Wo1, bo1, Wo2, bo2, Wo3, bo3, out);
    } else {
        edge_mfma_kernel<<<B_ * N_, 256, 0, stream>>>(
            xb, x, rel, W1t, W2t, b1, b2, Wo1, bo1, Wo2, bo2, Wo3, bo3, out);
    }
}

// Round 7
// 258.107 us; speedup vs baseline: 11.2346x; 1.3534x over previous
//
#include <hip/hip_runtime.h>

// GraphDecoder (NRI) — round 7: 32x32x16 MFMA, register-built H, glds staging.
// B=32, N=64, F=128, K=4, H=M=NH=256, E=4032. Edge e=i*63+jj: recv i, send j=jj+(jj>=i).
// h = relu(R[b,i] + S[b,j]);  R = x@W1[:,:128,:]+b1, S = x@W1[:,128:,:]

#define B_    32
#define N_    64
#define F_    128
#define K_    4
#define E_    4032

// ws layout (bytes) — peak 9,961,472 <= proven 9,994,240
#define WS_W2T 0u
#define WS_R   524288u
#define WS_S   4718592u
#define WS_AGG 8912896u
#define RS_K   524288u      // u16 stride per k in R/S tables

typedef unsigned short u16;
typedef u16    u16x8  __attribute__((ext_vector_type(8)));
typedef __bf16 bf16x8 __attribute__((ext_vector_type(8)));
typedef float  f32x4  __attribute__((ext_vector_type(4)));
typedef float  f32x16 __attribute__((ext_vector_type(16)));

__device__ __forceinline__ u16 f2bf(float f) {
    unsigned u; __builtin_memcpy(&u, &f, 4);
    return (u16)((u + 0x7FFFu + ((u >> 16) & 1u)) >> 16);
}
__device__ __forceinline__ float bf2f(u16 u) {
    unsigned v = ((unsigned)u) << 16;
    float f; __builtin_memcpy(&f, &v, 4); return f;
}
__device__ __forceinline__ bf16x8 bc8(u16x8 v) {
    bf16x8 r; __builtin_memcpy(&r, &v, 16); return r;
}
__device__ __forceinline__ void gl_lds16(const u16* g, u16* l) {
    // async 16B/lane global->LDS; dst is wave-uniform base (+lane*16 implicit)
    __builtin_amdgcn_global_load_lds(
        (const __attribute__((address_space(1))) void*)g,
        (__attribute__((address_space(3))) void*)l, 16, 0, 0);
}

// ---------------- prep: W2 f32 -> swizzled bf16 chunks ----------------
// chunk[(k*8+kc)] = 256 n-rows x 32 kk, row = 64B: unit u'=(u+n)&3 XOR-swizzle.
__global__ __launch_bounds__(256) void prep2_kernel(
    const float* __restrict__ W2, u16* __restrict__ W2t)
{
    unsigned gid = blockIdx.x * 256u + threadIdx.x;      // 262144
    unsigned k = gid >> 16, kk = (gid >> 8) & 255u, n = gid & 255u;
    unsigned kc = kk >> 5, kl = kk & 31u, u = kl >> 3, e = kl & 7u;
    unsigned up = (u + n) & 3u;
    W2t[(k * 8 + kc) * 8192 + n * 32 + up * 8 + e] = f2bf(W2[gid]);
}

// ---------------- R/S tables via MFMA (reads f32 directly) ----------------
// grid (k, half, b) = 256 blocks; block: 64 node-rows x 256 cols, K=128.
__global__ __launch_bounds__(256) void rs2_kernel(
    const float* __restrict__ x, const float* __restrict__ W1,
    const float* __restrict__ b1, u16* __restrict__ R, u16* __restrict__ S)
{
    __shared__ u16 ldsA[64 * 136];
    __shared__ u16 ldsW[32 * 136];
    const int tid = threadIdx.x, lane = tid & 63, w = tid >> 6;
    const int quad = lane >> 4, mloc = lane & 15;
    const int bx = blockIdx.x, k = bx >> 6, half = (bx >> 5) & 1, b = bx & 31;

    for (int idx = tid; idx < 8192; idx += 256) {
        int row = idx >> 7, col = idx & 127;
        ldsA[row * 136 + col] = f2bf(x[(b * 64 + row) * 128 + col]);
    }
    __syncthreads();

    bf16x8 aF[4];
#pragma unroll
    for (int ks = 0; ks < 4; ++ks)
        aF[ks] = *(const bf16x8*)&ldsA[(w * 16 + mloc) * 136 + quad * 8 + ks * 32];

    u16* dst = half ? S : R;
    for (int c = 0; c < 8; ++c) {
        __syncthreads();
        for (int idx = tid; idx < 4096; idx += 256) {
            int n = idx & 31, f = idx >> 5;
            ldsW[n * 136 + f] = f2bf(W1[(k * 256 + half * 128 + f) * 256 + c * 32 + n]);
        }
        __syncthreads();
#pragma unroll
        for (int nt = 0; nt < 2; ++nt) {
            f32x4 acc = (f32x4){0.f, 0.f, 0.f, 0.f};
            const int boff = (nt * 16 + mloc) * 136 + quad * 8;
#pragma unroll
            for (int ks = 0; ks < 4; ++ks)
                acc = __builtin_amdgcn_mfma_f32_16x16x32_bf16(
                    aF[ks], *(const bf16x8*)&ldsW[boff + ks * 32], acc, 0, 0, 0);
            const int n = c * 32 + nt * 16 + mloc;
            const float bias = half ? 0.f : b1[k * 256 + n];
#pragma unroll
            for (int r = 0; r < 4; ++r) {
                int row = w * 16 + quad * 4 + r;
                dst[(size_t)(k * 2048 + b * 64 + row) * 256 + n] = f2bf(acc[r] + bias);
            }
        }
    }
}

// ---------------- edge kernel: 32x32x16, reg A-frags, glds dbuf ----------------
__global__ __launch_bounds__(256, 3) void edge3_kernel(
    const u16* __restrict__ R, const u16* __restrict__ S,
    const float* __restrict__ rel, const u16* __restrict__ W2t,
    const float* __restrict__ b2, u16* __restrict__ aggb)
{
    __shared__ u16   WtS[2][8192];    // dbuf weight chunk (256 n x 32 kk, swizzled)
    __shared__ u16   ldsR[1024];      // R_i rows for 4 k
    __shared__ float rtS[256];
    __shared__ float aggS[256];

    const int tid  = threadIdx.x;
    const int lane = tid & 63;
    const int w    = tid >> 6;
    const int mt   = w & 1;           // m-tile (rows mt*32..+32)
    const int nh   = w >> 1;          // n-half (cols nh*128..+128)
    const int l31  = lane & 31;
    const int lh   = lane >> 5;
    const int bid  = blockIdx.x;
    const int b    = bid >> 6;
    const int i    = bid & 63;

    const int row = mt * 32 + l31;    // edge row this lane holds (A operand)
    int j = (row < i) ? row : row + 1;
    if (j > 63) j = 63;               // dummy row 63, masked by rtS=0

    // prefetch chunk idx=0 -> buf0 (each wave stages its quarter, 4x 1KB)
    {
        const u16* src = W2t + w * 2048;
        u16* dst = &WtS[0][w * 2048];
#pragma unroll
        for (int it = 0; it < 4; ++it)
            gl_lds16(src + it * 512 + lane * 8, dst + it * 512);
    }
    aggS[tid] = 0.f;
    {
        int r2 = tid >> 2, kk = tid & 3;
        rtS[tid] = (r2 < 63) ? rel[((b * E_) + i * 63 + r2) * K_ + kk] : 0.f;
    }
    if (tid < 128)
        *(u16x8*)&ldsR[(tid >> 5) * 256 + (tid & 31) * 8] =
            *(const u16x8*)&R[(size_t)((tid >> 5) * 2048 + b * 64 + i) * 256 + (tid & 31) * 8];
    __syncthreads();

    float amsg[4] = {0.f, 0.f, 0.f, 0.f};

    for (int k = 0; k < K_; ++k) {
        const u16* Sk = S + (size_t)k * RS_K + (size_t)(b * 64 + j) * 256;
        f32x16 acc[4];
#pragma unroll
        for (int nt = 0; nt < 4; ++nt) acc[nt] = (f32x16)(0.f);

        // software-pipelined S slices (16B per lane, two per chunk)
        u16x8 sa = *(const u16x8*)&Sk[lh * 8];
        u16x8 sb = *(const u16x8*)&Sk[16 + lh * 8];

        for (int kc = 0; kc < 8; ++kc) {
            const int idx = k * 8 + kc;
            // prefetch next weight chunk into other buffer
            if (idx < 31) {
                const u16* src = W2t + (idx + 1) * 8192 + w * 2048;
                u16* dst = &WtS[(idx + 1) & 1][w * 2048];
#pragma unroll
                for (int it = 0; it < 4; ++it)
                    gl_lds16(src + it * 512 + lane * 8, dst + it * 512);
            }
            // prefetch next S slices
            u16x8 na, nb;
            if (kc < 7) {
                na = *(const u16x8*)&Sk[(kc + 1) * 32 + lh * 8];
                nb = *(const u16x8*)&Sk[(kc + 1) * 32 + 16 + lh * 8];
            }
            // A-frags: relu(R + S), packed bf16 (kk slices kc*32+{0,16}+lh*8)
            u16x8 r0 = *(const u16x8*)&ldsR[k * 256 + kc * 32 + lh * 8];
            u16x8 r1 = *(const u16x8*)&ldsR[k * 256 + kc * 32 + 16 + lh * 8];
            u16x8 a0u, a1u;
#pragma unroll
            for (int e = 0; e < 8; ++e) {
                float v0 = bf2f(r0[e]) + bf2f(sa[e]);
                float v1 = bf2f(r1[e]) + bf2f(sb[e]);
                a0u[e] = f2bf(v0 > 0.f ? v0 : 0.f);
                a1u[e] = f2bf(v1 > 0.f ? v1 : 0.f);
            }
            bf16x8 a0 = bc8(a0u), a1 = bc8(a1u);
            const u16* buf = WtS[idx & 1];
#pragma unroll
            for (int nt = 0; nt < 4; ++nt) {
                const int rowB = nh * 128 + nt * 32 + l31;
                // ks2=0: u = lh; ks2=1: u = 2+lh; swizzle u' = (u+rowB)&3
                const int base = rowB * 32;
                bf16x8 b0 = *(const bf16x8*)&buf[base + (((lh)     + rowB) & 3) * 8];
                bf16x8 b1f = *(const bf16x8*)&buf[base + (((2 + lh) + rowB) & 3) * 8];
                acc[nt] = __builtin_amdgcn_mfma_f32_32x32x16_bf16(a0, b0,  acc[nt], 0, 0, 0);
                acc[nt] = __builtin_amdgcn_mfma_f32_32x32x16_bf16(a1, b1f, acc[nt], 0, 0, 0);
            }
            sa = na; sb = nb;
            __syncthreads();
        }
        // per-k epilogue: bias + relu + rel_type weight, fold rows into amsg
        float bias[4];
#pragma unroll
        for (int nt = 0; nt < 4; ++nt) bias[nt] = b2[k * 256 + nh * 128 + nt * 32 + l31];
#pragma unroll
        for (int reg = 0; reg < 16; ++reg) {
            const int rrow = mt * 32 + (reg & 3) + 8 * (reg >> 2) + 4 * lh;
            const float rw = rtS[rrow * 4 + k];
#pragma unroll
            for (int nt = 0; nt < 4; ++nt) {
                float v = acc[nt][reg] + bias[nt];
                v = v > 0.f ? v : 0.f;
                amsg[nt] += rw * v;
            }
        }
    }

#pragma unroll
    for (int nt = 0; nt < 4; ++nt)
        atomicAdd(&aggS[nh * 128 + nt * 32 + l31], amsg[nt]);
    __syncthreads();
    aggb[(size_t)bid * 256 + tid] = f2bf(aggS[tid]);
}

// ---------------- output MLP: 32 blocks x 64 rows, MFMA, LDS p1/p2 ----------------
__global__ __launch_bounds__(256) void outmlp_kernel(
    const float* __restrict__ x, const u16* __restrict__ aggb,
    const float* __restrict__ Wo1, const float* __restrict__ bo1,
    const float* __restrict__ Wo2, const float* __restrict__ bo2,
    const float* __restrict__ Wo3, const float* __restrict__ bo3,
    float* __restrict__ out)
{
    __shared__ u16 p1S[64 * 264];
    __shared__ u16 p2S[64 * 264];
    const int tid = threadIdx.x, lane = tid & 63, w = tid >> 6;
    const int quad = lane >> 4, mloc = lane & 15;
    const int row0 = blockIdx.x * 64;

    // ---- layer 1: p1 = relu(aug @ Wo1 + bo1), aug = [x | agg], K=384 ----
    {
        f32x4 acc[4][4];
#pragma unroll
        for (int mtt = 0; mtt < 4; ++mtt)
#pragma unroll
            for (int nt = 0; nt < 4; ++nt) acc[mtt][nt] = (f32x4){0.f, 0.f, 0.f, 0.f};
        for (int kk = 0; kk < 12; ++kk) {
            bf16x8 aF[4];
#pragma unroll
            for (int mtt = 0; mtt < 4; ++mtt) {
                const int row = row0 + mtt * 16 + mloc;
                if (kk < 4) {
                    const float* p = &x[row * 128 + kk * 32 + quad * 8];
                    u16x8 t;
#pragma unroll
                    for (int e = 0; e < 8; ++e) t[e] = f2bf(p[e]);
                    aF[mtt] = bc8(t);
                } else {
                    aF[mtt] = bc8(*(const u16x8*)&aggb[(size_t)row * 256 + (kk - 4) * 32 + quad * 8]);
                }
            }
#pragma unroll
            for (int nt = 0; nt < 4; ++nt) {
                const int n = (w * 4 + nt) * 16 + mloc;
                u16x8 t;
#pragma unroll
                for (int e = 0; e < 8; ++e) t[e] = f2bf(Wo1[(kk * 32 + quad * 8 + e) * 256 + n]);
                bf16x8 bF = bc8(t);
#pragma unroll
                for (int mtt = 0; mtt < 4; ++mtt)
                    acc[mtt][nt] = __builtin_amdgcn_mfma_f32_16x16x32_bf16(aF[mtt], bF, acc[mtt][nt], 0, 0, 0);
            }
        }
#pragma unroll
        for (int nt = 0; nt < 4; ++nt) {
            const int n = (w * 4 + nt) * 16 + mloc;
            const float bias = bo1[n];
#pragma unroll
            for (int mtt = 0; mtt < 4; ++mtt)
#pragma unroll
                for (int r = 0; r < 4; ++r) {
                    float v = acc[mtt][nt][r] + bias;
                    p1S[(mtt * 16 + quad * 4 + r) * 264 + n] = f2bf(v > 0.f ? v : 0.f);
                }
        }
    }
    __syncthreads();

    // ---- layer 2: p2 = relu(p1 @ Wo2 + bo2), K=256 ----
    {
        f32x4 acc[4][4];
#pragma unroll
        for (int mtt = 0; mtt < 4; ++mtt)
#pragma unroll
            for (int nt = 0; nt < 4; ++nt) acc[mtt][nt] = (f32x4){0.f, 0.f, 0.f, 0.f};
        for (int kk = 0; kk < 8; ++kk) {
            bf16x8 aF[4];
#pragma unroll
            for (int mtt = 0; mtt < 4; ++mtt)
                aF[mtt] = *(const bf16x8*)&p1S[(mtt * 16 + mloc) * 264 + kk * 32 + quad * 8];
#pragma unroll
            for (int nt = 0; nt < 4; ++nt) {
                const int n = (w * 4 + nt) * 16 + mloc;
                u16x8 t;
#pragma unroll
                for (int e = 0; e < 8; ++e) t[e] = f2bf(Wo2[(kk * 32 + quad * 8 + e) * 256 + n]);
                bf16x8 bF = bc8(t);
#pragma unroll
                for (int mtt = 0; mtt < 4; ++mtt)
                    acc[mtt][nt] = __builtin_amdgcn_mfma_f32_16x16x32_bf16(aF[mtt], bF, acc[mtt][nt], 0, 0, 0);
            }
        }
#pragma unroll
        for (int nt = 0; nt < 4; ++nt) {
            const int n = (w * 4 + nt) * 16 + mloc;
            const float bias = bo2[n];
#pragma unroll
            for (int mtt = 0; mtt < 4; ++mtt)
#pragma unroll
                for (int r = 0; r < 4; ++r) {
                    float v = acc[mtt][nt][r] + bias;
                    p2S[(mtt * 16 + quad * 4 + r) * 264 + n] = f2bf(v > 0.f ? v : 0.f);
                }
        }
    }
    __syncthreads();

    // ---- layer 3: out = x + p2 @ Wo3 + bo3, K=256, N=128 ----
    {
        f32x4 acc[4][2];
#pragma unroll
        for (int mtt = 0; mtt < 4; ++mtt)
#pragma unroll
            for (int nt = 0; nt < 2; ++nt) acc[mtt][nt] = (f32x4){0.f, 0.f, 0.f, 0.f};
        for (int kk = 0; kk < 8; ++kk) {
            bf16x8 aF[4];
#pragma unroll
            for (int mtt = 0; mtt < 4; ++mtt)
                aF[mtt] = *(const bf16x8*)&p2S[(mtt * 16 + mloc) * 264 + kk * 32 + quad * 8];
#pragma unroll
            for (int nt = 0; nt < 2; ++nt) {
                const int n = (w * 2 + nt) * 16 + mloc;
                u16x8 t;
#pragma unroll
                for (int e = 0; e < 8; ++e) t[e] = f2bf(Wo3[(kk * 32 + quad * 8 + e) * 128 + n]);
                bf16x8 bF = bc8(t);
#pragma unroll
                for (int mtt = 0; mtt < 4; ++mtt)
                    acc[mtt][nt] = __builtin_amdgcn_mfma_f32_16x16x32_bf16(aF[mtt], bF, acc[mtt][nt], 0, 0, 0);
            }
        }
#pragma unroll
        for (int nt = 0; nt < 2; ++nt) {
            const int n = (w * 2 + nt) * 16 + mloc;
            const float bias = bo3[n];
#pragma unroll
            for (int mtt = 0; mtt < 4; ++mtt)
#pragma unroll
                for (int r = 0; r < 4; ++r) {
                    const int grow = row0 + mtt * 16 + quad * 4 + r;
                    out[grow * 128 + n] = x[grow * 128 + n] + acc[mtt][nt][r] + bias;
                }
        }
    }
}

extern "C" void kernel_launch(void* const* d_in, const int* in_sizes, int n_in,
                              void* d_out, int out_size, void* d_ws, size_t ws_size,
                              hipStream_t stream) {
    const float* x   = (const float*)d_in[0];
    const float* rel = (const float*)d_in[1];
    const float* W1  = (const float*)d_in[4];
    const float* b1  = (const float*)d_in[5];
    const float* W2  = (const float*)d_in[6];
    const float* b2  = (const float*)d_in[7];
    const float* Wo1 = (const float*)d_in[8];
    const float* bo1 = (const float*)d_in[9];
    const float* Wo2 = (const float*)d_in[10];
    const float* bo2 = (const float*)d_in[11];
    const float* Wo3 = (const float*)d_in[12];
    const float* bo3 = (const float*)d_in[13];
    float* out = (float*)d_out;

    char* ws = (char*)d_ws;
    u16* W2t  = (u16*)(ws + WS_W2T);
    u16* R    = (u16*)(ws + WS_R);
    u16* S    = (u16*)(ws + WS_S);
    u16* aggb = (u16*)(ws + WS_AGG);

    prep2_kernel<<<1024, 256, 0, stream>>>(W2, W2t);
    rs2_kernel<<<256, 256, 0, stream>>>(x, W1, b1, R, S);
    edge3_kernel<<<B_ * N_, 256, 0, stream>>>(R, S, rel, W2t, b2, aggb);
    outmlp_kernel<<<32, 256, 0, stream>>>(x, aggb, Wo1, bo1, Wo2, bo2, Wo3, bo3, out);
}

// Round 8
// 240.268 us; speedup vs baseline: 12.0688x; 1.0742x over previous
//
#include <hip/hip_runtime.h>

// GraphDecoder (NRI) — round 8: 256-row edge blocks (512 thr), conflict-free
// W2t layout, native bf16 cvt A-build, atomic-free aggregation.
// B=32, N=64, F=128, K=4, H=M=NH=256, E=4032. Edge e=i*63+jj: recv i, send j=jj+(jj>=i).
// h = relu(R[b,i] + S[b,j]);  R = x@W1[:,:128,:]+b1, S = x@W1[:,128:,:]

#define B_ 32
#define N_ 64
#define F_ 128
#define K_ 4
#define E_ 4032

// ws layout (bytes): total 9,961,472 <= proven 9,994,240
#define WS_W2T 0u
#define WS_R   524288u
#define WS_S   4718592u
#define WS_AGG 8912896u

typedef unsigned short u16;
typedef u16    u16x4  __attribute__((ext_vector_type(4)));
typedef u16    u16x8  __attribute__((ext_vector_type(8)));
typedef __bf16 bf16x8 __attribute__((ext_vector_type(8)));
typedef float  f32x4  __attribute__((ext_vector_type(4)));
typedef float  f32x16 __attribute__((ext_vector_type(16)));

__device__ __forceinline__ u16 f2bf(float f) {
    unsigned u; __builtin_memcpy(&u, &f, 4);
    return (u16)((u + 0x7FFFu + ((u >> 16) & 1u)) >> 16);
}
__device__ __forceinline__ float bf2f(u16 u) {
    unsigned v = ((unsigned)u) << 16;
    float f; __builtin_memcpy(&f, &v, 4); return f;
}
__device__ __forceinline__ void gl_lds16(const u16* g, u16* l) {
    __builtin_amdgcn_global_load_lds(
        (const __attribute__((address_space(1))) void*)g,
        (__attribute__((address_space(3))) void*)l, 16, 0, 0);
}

// ---------------- fused prep (W2 -> chunked bf16) + R/S tables ----------------
// blocks 0..1023: W2 transpose/convert, coalesced dst.
// blocks 1024..1279: R/S via MFMA (R7-proven body).
__global__ __launch_bounds__(256) void prep_rs_kernel(
    const float* __restrict__ W2, const float* __restrict__ x,
    const float* __restrict__ W1, const float* __restrict__ b1,
    u16* __restrict__ W2t, u16* __restrict__ R, u16* __restrict__ S)
{
    __shared__ u16 ldsA[64 * 136];
    __shared__ u16 ldsW[32 * 136];
    const int tid = threadIdx.x;

    if (blockIdx.x < 1024) {
        // W2t[chunk=k*8+kc][g=ks2*2+lh][n(256)][e(8)] = W2[k][kk][n]
        unsigned gid = blockIdx.x * 256u + tid;
        unsigned chunk = gid >> 13, r = gid & 8191u;
        unsigned g = r >> 11, n = (r >> 3) & 255u, e = r & 7u;
        unsigned k = chunk >> 3, kc = chunk & 7u, ks2 = g >> 1, lhh = g & 1u;
        unsigned kk = kc * 32u + ks2 * 16u + lhh * 8u + e;
        W2t[gid] = f2bf(W2[(k * 256u + kk) * 256u + n]);
        return;
    }

    const int lane = tid & 63, w = tid >> 6;
    const int quad = lane >> 4, mloc = lane & 15;
    const int bx = blockIdx.x - 1024;
    const int k = bx >> 6, half = (bx >> 5) & 1, b = bx & 31;

    for (int idx = tid; idx < 2048; idx += 256) {      // x -> bf16 LDS (float4)
        int row = idx >> 5, c4 = idx & 31;
        f32x4 v = *(const f32x4*)&x[(b * 64 + row) * 128 + c4 * 4];
        u16x4 o;
#pragma unroll
        for (int e = 0; e < 4; ++e) o[e] = f2bf(v[e]);
        *(u16x4*)&ldsA[row * 136 + c4 * 4] = o;
    }
    __syncthreads();

    bf16x8 aF[4];
#pragma unroll
    for (int ks = 0; ks < 4; ++ks)
        aF[ks] = *(const bf16x8*)&ldsA[(w * 16 + mloc) * 136 + quad * 8 + ks * 32];

    u16* dst = half ? S : R;
    for (int c = 0; c < 8; ++c) {
        __syncthreads();
        for (int idx = tid; idx < 4096; idx += 256) {
            int n = idx & 31, f = idx >> 5;
            ldsW[n * 136 + f] = f2bf(W1[(k * 256 + half * 128 + f) * 256 + c * 32 + n]);
        }
        __syncthreads();
#pragma unroll
        for (int nt = 0; nt < 2; ++nt) {
            f32x4 acc = (f32x4){0.f, 0.f, 0.f, 0.f};
            const int boff = (nt * 16 + mloc) * 136 + quad * 8;
#pragma unroll
            for (int ks = 0; ks < 4; ++ks)
                acc = __builtin_amdgcn_mfma_f32_16x16x32_bf16(
                    aF[ks], *(const bf16x8*)&ldsW[boff + ks * 32], acc, 0, 0, 0);
            const int n = c * 32 + nt * 16 + mloc;
            const float bias = half ? 0.f : b1[k * 256 + n];
#pragma unroll
            for (int r = 0; r < 4; ++r) {
                int row = w * 16 + quad * 4 + r;
                dst[(size_t)(k * 2048 + b * 64 + row) * 256 + n] = f2bf(acc[r] + bias);
            }
        }
    }
}

// ---------------- edge kernel: 256 rows (4 receivers) per block, 8 waves ----------------
// wave w: receiver rh=w>>1 (rows rh*64..+63 = 2 m-tiles), n-half nh=w&1 (4 n-tiles).
__global__ __launch_bounds__(512, 2) void edge4_kernel(
    const u16* __restrict__ R, const u16* __restrict__ S,
    const float* __restrict__ rel, const u16* __restrict__ W2t,
    const float* __restrict__ b2, u16* __restrict__ aggb)
{
    __shared__ u16   WtS[2][8192];   // dbuf chunk: [g][n][8], conflict-free B reads
    __shared__ float Rf[4][4][256];  // receiver R rows, unpacked f32
    __shared__ float rtS[4][256];    // [k][block-row] rel_type

    const int tid  = threadIdx.x;
    const int lane = tid & 63;
    const int w    = tid >> 6;       // 0..7
    const int rh   = w >> 1;         // receiver 0..3
    const int nh   = w & 1;          // n-half
    const int l31  = lane & 31;
    const int lh   = lane >> 5;
    const int bid  = blockIdx.x;
    const int b    = bid >> 4;
    const int i0   = (bid & 15) * 4;
    const int i    = i0 + rh;

    // prefetch chunk 0 (each wave stages 2KB)
    {
        const u16* src = W2t + w * 1024;
        u16* dstp = &WtS[0][w * 1024];
        gl_lds16(src + lane * 8, dstp);
        gl_lds16(src + 512 + lane * 8, dstp + 512);
    }
    // rtS[k][row]: row=recv*64+jj
    for (int t = tid; t < 1024; t += 512) {
        int k = t >> 8, row = t & 255;
        int recv = row >> 6, jj = row & 63, ii = i0 + recv;
        rtS[k][row] = (jj < 63) ? rel[((size_t)(b * E_) + ii * 63 + jj) * 4 + k] : 0.f;
    }
    // Rf: unpack receiver R rows to f32
    {
        int slice = tid >> 5, e8 = tid & 31;
        int recv = slice >> 2, k = slice & 3;
        u16x8 t8 = *(const u16x8*)&R[((size_t)(k * 2048 + b * 64 + i0 + recv)) * 256 + e8 * 8];
        f32x4 lo, hi;
#pragma unroll
        for (int e = 0; e < 4; ++e) { lo[e] = bf2f(t8[e]); hi[e] = bf2f(t8[4 + e]); }
        *(f32x4*)&Rf[recv][k][e8 * 8]     = lo;
        *(f32x4*)&Rf[recv][k][e8 * 8 + 4] = hi;
    }
    // per-lane sender row pointers (2 m-tiles)
    const u16* Srow[2];
#pragma unroll
    for (int mt2 = 0; mt2 < 2; ++mt2) {
        int jj = mt2 * 32 + l31;
        int j = (jj < i) ? jj : jj + 1;
        if (j > 63) j = 63;            // dummy jj=63, masked by rtS=0
        Srow[mt2] = S + (size_t)(b * 64 + j) * 256;
    }
    __syncthreads();

    float amsg[4] = {0.f, 0.f, 0.f, 0.f};

    for (int k = 0; k < K_; ++k) {
        f32x16 acc[2][4];
#pragma unroll
        for (int mt2 = 0; mt2 < 2; ++mt2)
#pragma unroll
            for (int nt = 0; nt < 4; ++nt) acc[mt2][nt] = (f32x16)(0.f);

        const u16* Sk0 = Srow[0] + (size_t)k * 524288;
        const u16* Sk1 = Srow[1] + (size_t)k * 524288;

        for (int kc = 0; kc < 8; ++kc) {
            const int idx = k * 8 + kc;
            // S slices for this step (issue early)
            u16x8 sv[2][2];
#pragma unroll
            for (int ks2 = 0; ks2 < 2; ++ks2) {
                sv[ks2][0] = *(const u16x8*)&Sk0[kc * 32 + ks2 * 16 + lh * 8];
                sv[ks2][1] = *(const u16x8*)&Sk1[kc * 32 + ks2 * 16 + lh * 8];
            }
            // prefetch next weight chunk
            if (idx < 31) {
                const u16* src = W2t + (size_t)(idx + 1) * 8192 + w * 1024;
                u16* dstp = &WtS[(idx + 1) & 1][w * 1024];
                gl_lds16(src + lane * 8, dstp);
                gl_lds16(src + 512 + lane * 8, dstp + 512);
            }
            const u16* buf = WtS[idx & 1];
#pragma unroll
            for (int ks2 = 0; ks2 < 2; ++ks2) {
                // A-frags: relu(R + S) with native bf16 cvt
                const float* rp = &Rf[rh][k][kc * 32 + ks2 * 16 + lh * 8];
                f32x4 r0 = *(const f32x4*)rp, r1 = *(const f32x4*)(rp + 4);
                bf16x8 A[2];
#pragma unroll
                for (int mt2 = 0; mt2 < 2; ++mt2) {
                    bf16x8 a;
#pragma unroll
                    for (int e = 0; e < 4; ++e) {
                        a[e]     = (__bf16)fmaxf(r0[e] + bf2f(sv[ks2][mt2][e]),     0.f);
                        a[4 + e] = (__bf16)fmaxf(r1[e] + bf2f(sv[ks2][mt2][4 + e]), 0.f);
                    }
                    A[mt2] = a;
                }
#pragma unroll
                for (int nt = 0; nt < 4; ++nt) {
                    bf16x8 Bf = *(const bf16x8*)&buf[(ks2 * 2 + lh) * 2048
                                                     + (nh * 128 + nt * 32 + l31) * 8];
                    acc[0][nt] = __builtin_amdgcn_mfma_f32_32x32x16_bf16(A[0], Bf, acc[0][nt], 0, 0, 0);
                    acc[1][nt] = __builtin_amdgcn_mfma_f32_32x32x16_bf16(A[1], Bf, acc[1][nt], 0, 0, 0);
                }
            }
            __syncthreads();
        }
        // per-k epilogue: bias+relu, rel_type-weighted row-fold (f32x4 rt reads)
        float bias_[4];
#pragma unroll
        for (int nt = 0; nt < 4; ++nt) bias_[nt] = b2[k * 256 + nh * 128 + nt * 32 + l31];
#pragma unroll
        for (int mt2 = 0; mt2 < 2; ++mt2)
#pragma unroll
            for (int nt = 0; nt < 4; ++nt) {
                float s = 0.f;
#pragma unroll
                for (int q = 0; q < 4; ++q) {
                    f32x4 rt4 = *(const f32x4*)&rtS[k][rh * 64 + mt2 * 32 + q * 8 + 4 * lh];
#pragma unroll
                    for (int e = 0; e < 4; ++e) {
                        float v = acc[mt2][nt][q * 4 + e] + bias_[nt];
                        v = v > 0.f ? v : 0.f;
                        s += rt4[e] * v;
                    }
                }
                amsg[nt] += s;
            }
    }

    // fold lh halves; unique writer per agg slot (no atomics)
    const int iglob = b * 64 + i;
#pragma unroll
    for (int nt = 0; nt < 4; ++nt) {
        float s = amsg[nt] + __shfl_xor(amsg[nt], 32);
        if (lh == 0)
            aggb[(size_t)iglob * 256 + nh * 128 + nt * 32 + l31] = f2bf(s);
    }
}

// ---------------- output MLP: 128 blocks x 16 rows, MFMA ----------------
__global__ __launch_bounds__(256) void outmlp_kernel(
    const float* __restrict__ x, const u16* __restrict__ aggb,
    const float* __restrict__ Wo1, const float* __restrict__ bo1,
    const float* __restrict__ Wo2, const float* __restrict__ bo2,
    const float* __restrict__ Wo3, const float* __restrict__ bo3,
    float* __restrict__ out)
{
    __shared__ u16 p1S[16 * 264];
    __shared__ u16 p2S[16 * 264];
    const int tid = threadIdx.x, lane = tid & 63, w = tid >> 6;
    const int quad = lane >> 4, mloc = lane & 15;
    const int row0 = blockIdx.x * 16;

    {   // layer 1: K=384, aug=[x | agg]
        f32x4 acc[4];
#pragma unroll
        for (int nt = 0; nt < 4; ++nt) acc[nt] = (f32x4){0.f, 0.f, 0.f, 0.f};
        for (int kk = 0; kk < 12; ++kk) {
            bf16x8 aF;
            const int row = row0 + mloc;
            if (kk < 4) {
                const float* p = &x[row * 128 + kk * 32 + quad * 8];
                u16x8 t;
#pragma unroll
                for (int e = 0; e < 8; ++e) t[e] = f2bf(p[e]);
                __builtin_memcpy(&aF, &t, 16);
            } else {
                aF = *(const bf16x8*)&aggb[(size_t)row * 256 + (kk - 4) * 32 + quad * 8];
            }
#pragma unroll
            for (int nt = 0; nt < 4; ++nt) {
                const int n = (w * 4 + nt) * 16 + mloc;
                u16x8 t;
#pragma unroll
                for (int e = 0; e < 8; ++e) t[e] = f2bf(Wo1[(kk * 32 + quad * 8 + e) * 256 + n]);
                bf16x8 bF; __builtin_memcpy(&bF, &t, 16);
                acc[nt] = __builtin_amdgcn_mfma_f32_16x16x32_bf16(aF, bF, acc[nt], 0, 0, 0);
            }
        }
#pragma unroll
        for (int nt = 0; nt < 4; ++nt) {
            const int n = (w * 4 + nt) * 16 + mloc;
            const float bias = bo1[n];
#pragma unroll
            for (int r = 0; r < 4; ++r) {
                float v = acc[nt][r] + bias;
                p1S[(quad * 4 + r) * 264 + n] = f2bf(v > 0.f ? v : 0.f);
            }
        }
    }
    __syncthreads();
    {   // layer 2: K=256
        f32x4 acc[4];
#pragma unroll
        for (int nt = 0; nt < 4; ++nt) acc[nt] = (f32x4){0.f, 0.f, 0.f, 0.f};
        for (int kk = 0; kk < 8; ++kk) {
            bf16x8 aF = *(const bf16x8*)&p1S[mloc * 264 + kk * 32 + quad * 8];
#pragma unroll
            for (int nt = 0; nt < 4; ++nt) {
                const int n = (w * 4 + nt) * 16 + mloc;
                u16x8 t;
#pragma unroll
                for (int e = 0; e < 8; ++e) t[e] = f2bf(Wo2[(kk * 32 + quad * 8 + e) * 256 + n]);
                bf16x8 bF; __builtin_memcpy(&bF, &t, 16);
                acc[nt] = __builtin_amdgcn_mfma_f32_16x16x32_bf16(aF, bF, acc[nt], 0, 0, 0);
            }
        }
#pragma unroll
        for (int nt = 0; nt < 4; ++nt) {
            const int n = (w * 4 + nt) * 16 + mloc;
            const float bias = bo2[n];
#pragma unroll
            for (int r = 0; r < 4; ++r) {
                float v = acc[nt][r] + bias;
                p2S[(quad * 4 + r) * 264 + n] = f2bf(v > 0.f ? v : 0.f);
            }
        }
    }
    __syncthreads();
    {   // layer 3: N=128, residual add
        f32x4 acc[2];
#pragma unroll
        for (int nt = 0; nt < 2; ++nt) acc[nt] = (f32x4){0.f, 0.f, 0.f, 0.f};
        for (int kk = 0; kk < 8; ++kk) {
            bf16x8 aF = *(const bf16x8*)&p2S[mloc * 264 + kk * 32 + quad * 8];
#pragma unroll
            for (int nt = 0; nt < 2; ++nt) {
                const int n = (w * 2 + nt) * 16 + mloc;
                u16x8 t;
#pragma unroll
                for (int e = 0; e < 8; ++e) t[e] = f2bf(Wo3[(kk * 32 + quad * 8 + e) * 128 + n]);
                bf16x8 bF; __builtin_memcpy(&bF, &t, 16);
                acc[nt] = __builtin_amdgcn_mfma_f32_16x16x32_bf16(aF, bF, acc[nt], 0, 0, 0);
            }
        }
#pragma unroll
        for (int nt = 0; nt < 2; ++nt) {
            const int n = (w * 2 + nt) * 16 + mloc;
            const float bias = bo3[n];
#pragma unroll
            for (int r = 0; r < 4; ++r) {
                const int grow = row0 + quad * 4 + r;
                out[grow * 128 + n] = x[grow * 128 + n] + acc[nt][r] + bias;
            }
        }
    }
}

extern "C" void kernel_launch(void* const* d_in, const int* in_sizes, int n_in,
                              void* d_out, int out_size, void* d_ws, size_t ws_size,
                              hipStream_t stream) {
    const float* x   = (const float*)d_in[0];
    const float* rel = (const float*)d_in[1];
    const float* W1  = (const float*)d_in[4];
    const float* b1  = (const float*)d_in[5];
    const float* W2  = (const float*)d_in[6];
    const float* b2  = (const float*)d_in[7];
    const float* Wo1 = (const float*)d_in[8];
    const float* bo1 = (const float*)d_in[9];
    const float* Wo2 = (const float*)d_in[10];
    const float* bo2 = (const float*)d_in[11];
    const float* Wo3 = (const float*)d_in[12];
    const float* bo3 = (const float*)d_in[13];
    float* out = (float*)d_out;

    char* ws = (char*)d_ws;
    u16* W2t  = (u16*)(ws + WS_W2T);
    u16* R    = (u16*)(ws + WS_R);
    u16* S    = (u16*)(ws + WS_S);
    u16* aggb = (u16*)(ws + WS_AGG);

    prep_rs_kernel<<<1280, 256, 0, stream>>>(W2, x, W1, b1, W2t, R, S);
    edge4_kernel<<<512, 512, 0, stream>>>(R, S, rel, W2t, b2, aggb);
    outmlp_kernel<<<128, 256, 0, stream>>>(x, aggb, Wo1, bo1, Wo2, bo2, Wo3, bo3, out);
}

// Round 9
// 217.499 us; speedup vs baseline: 13.3322x; 1.1047x over previous
//
#include <hip/hip_runtime.h>

// GraphDecoder (NRI) — round 9: self-edge trick, H-in-LDS (built once), mt=4
// B-reuse, 1 barrier/kc, grid 1024; coalesced-staged output MLP.
// B=32, N=64, F=128, K=4, H=M=NH=256, E=4032.
// h = relu(R[b,i] + S[b,j]), j=0..63, rel-weight 0 for j==i.

#define B_ 32
#define N_ 64
#define F_ 128
#define K_ 4
#define E_ 4032

// ws layout (bytes): total 9,961,472 <= proven 9,994,240
#define WS_W2T 0u
#define WS_R   524288u
#define WS_S   4718592u
#define WS_AGG 8912896u

typedef unsigned short u16;
typedef u16    u16x4  __attribute__((ext_vector_type(4)));
typedef u16    u16x8  __attribute__((ext_vector_type(8)));
typedef __bf16 bf16x8 __attribute__((ext_vector_type(8)));
typedef float  f32x4  __attribute__((ext_vector_type(4)));
typedef float  f32x16 __attribute__((ext_vector_type(16)));

__device__ __forceinline__ u16 f2bf(float f) {
    unsigned u; __builtin_memcpy(&u, &f, 4);
    return (u16)((u + 0x7FFFu + ((u >> 16) & 1u)) >> 16);
}
__device__ __forceinline__ float bf2f(u16 u) {
    unsigned v = ((unsigned)u) << 16;
    float f; __builtin_memcpy(&f, &v, 4); return f;
}
__device__ __forceinline__ void gl_lds16(const u16* g, u16* l) {
    __builtin_amdgcn_global_load_lds(
        (const __attribute__((address_space(1))) void*)g,
        (__attribute__((address_space(3))) void*)l, 16, 0, 0);
}

// ---------------- fused prep (W2 -> cf bf16 chunks) + R/S tables (R8-proven) ----------------
__global__ __launch_bounds__(256) void prep_rs_kernel(
    const float* __restrict__ W2, const float* __restrict__ x,
    const float* __restrict__ W1, const float* __restrict__ b1,
    u16* __restrict__ W2t, u16* __restrict__ R, u16* __restrict__ S)
{
    __shared__ u16 ldsA[64 * 136];
    __shared__ u16 ldsW[32 * 136];
    const int tid = threadIdx.x;

    if (blockIdx.x < 1024) {
        // W2t[chunk=k*8+kc][g=ks2*2+lh][n(256)][e(8)] = W2[k][kk][n]
        unsigned gid = blockIdx.x * 256u + tid;
        unsigned chunk = gid >> 13, r = gid & 8191u;
        unsigned g = r >> 11, n = (r >> 3) & 255u, e = r & 7u;
        unsigned k = chunk >> 3, kc = chunk & 7u, ks2 = g >> 1, lhh = g & 1u;
        unsigned kk = kc * 32u + ks2 * 16u + lhh * 8u + e;
        W2t[gid] = f2bf(W2[(k * 256u + kk) * 256u + n]);
        return;
    }

    const int lane = tid & 63, w = tid >> 6;
    const int quad = lane >> 4, mloc = lane & 15;
    const int bx = blockIdx.x - 1024;
    const int k = bx >> 6, half = (bx >> 5) & 1, b = bx & 31;

    for (int idx = tid; idx < 2048; idx += 256) {
        int row = idx >> 5, c4 = idx & 31;
        f32x4 v = *(const f32x4*)&x[(b * 64 + row) * 128 + c4 * 4];
        u16x4 o;
#pragma unroll
        for (int e = 0; e < 4; ++e) o[e] = f2bf(v[e]);
        *(u16x4*)&ldsA[row * 136 + c4 * 4] = o;
    }
    __syncthreads();

    bf16x8 aF[4];
#pragma unroll
    for (int ks = 0; ks < 4; ++ks)
        aF[ks] = *(const bf16x8*)&ldsA[(w * 16 + mloc) * 136 + quad * 8 + ks * 32];

    u16* dst = half ? S : R;
    for (int c = 0; c < 8; ++c) {
        __syncthreads();
        for (int idx = tid; idx < 4096; idx += 256) {
            int n = idx & 31, f = idx >> 5;
            ldsW[n * 136 + f] = f2bf(W1[(k * 256 + half * 128 + f) * 256 + c * 32 + n]);
        }
        __syncthreads();
#pragma unroll
        for (int nt = 0; nt < 2; ++nt) {
            f32x4 acc = (f32x4){0.f, 0.f, 0.f, 0.f};
            const int boff = (nt * 16 + mloc) * 136 + quad * 8;
#pragma unroll
            for (int ks = 0; ks < 4; ++ks)
                acc = __builtin_amdgcn_mfma_f32_16x16x32_bf16(
                    aF[ks], *(const bf16x8*)&ldsW[boff + ks * 32], acc, 0, 0, 0);
            const int n = c * 32 + nt * 16 + mloc;
            const float bias = half ? 0.f : b1[k * 256 + n];
#pragma unroll
            for (int r = 0; r < 4; ++r) {
                int row = w * 16 + quad * 4 + r;
                dst[(size_t)(k * 2048 + b * 64 + row) * 256 + n] = f2bf(acc[r] + bias);
            }
        }
    }
}

// ---------------- edge kernel: 2 receivers, 128 rows, mt=4 x nt=2 per wave ----------------
__global__ __launch_bounds__(256, 2) void edge5_kernel(
    const u16* __restrict__ R, const u16* __restrict__ S,
    const float* __restrict__ rel, const u16* __restrict__ W2t,
    const float* __restrict__ b2, u16* __restrict__ aggb)
{
    __shared__ u16   WtS[2][8192];       // W2 chunk dbuf (cf [g][n][8])
    __shared__ u16   HS[2][4][128][8];   // H chunk dbuf: [g][row=recv*64+j][8kk]
    __shared__ float Rf[2][4][256];      // receiver R rows, f32
    __shared__ float rtS[2][4][64];      // rel_type [recv][k][j], self=0

    const int tid  = threadIdx.x;
    const int lane = tid & 63;
    const int w    = tid >> 6;           // n-quarter 0..3
    const int l31  = lane & 31;
    const int lh   = lane >> 5;
    const int bid  = blockIdx.x;
    const int b    = bid >> 5;
    const int i0   = (bid & 31) * 2;
    const int brow = tid >> 2;           // H-build row (sender j) 0..63
    const int bc   = tid & 3;            // H-build kk-8-group 0..3

    // glds W chunk 0 (each wave stages its 4KB quarter)
    {
        const u16* src = W2t + w * 2048;
        u16* dst = &WtS[0][w * 2048];
#pragma unroll
        for (int it2 = 0; it2 < 4; ++it2)
            gl_lds16(src + it2 * 512 + lane * 8, dst + it2 * 512);
    }
    // rtS: self-edge trick (j==i -> 0; else jj = j - (j>i))
    for (int t = tid; t < 512; t += 256) {
        int recv = t >> 8, rem = t & 255, k = rem >> 6, j = rem & 63;
        int i = i0 + recv;
        float v = 0.f;
        if (j != i) {
            int jj = j - (j > i);
            v = rel[((size_t)(b * E_) + i * 63 + jj) * 4 + k];
        }
        rtS[recv][k][j] = v;
    }
    // Rf: unpack both receivers' R rows to f32
    {
        int recv = tid >> 7, k = (tid >> 5) & 3, e8 = tid & 31;
        u16x8 t8 = *(const u16x8*)&R[((size_t)(k * 2048 + b * 64 + i0 + recv)) * 256 + e8 * 8];
#pragma unroll
        for (int e = 0; e < 8; ++e) Rf[recv][k][e8 * 8 + e] = bf2f(t8[e]);
    }
    // S slice for chunk 0 (rows contiguous -> coalesced)
    u16x8 sv = *(const u16x8*)&S[((size_t)(b * 64 + brow)) * 256 + bc * 8];
    __syncthreads();

    // build H chunk 0
    {
#pragma unroll
        for (int recv = 0; recv < 2; ++recv) {
            const float* rp = &Rf[recv][0][bc * 8];
            f32x4 r0 = *(const f32x4*)rp, r1 = *(const f32x4*)(rp + 4);
            bf16x8 o;
#pragma unroll
            for (int e = 0; e < 4; ++e) {
                o[e]     = (__bf16)fmaxf(r0[e] + bf2f(sv[e]),     0.f);
                o[4 + e] = (__bf16)fmaxf(r1[e] + bf2f(sv[4 + e]), 0.f);
            }
            *(bf16x8*)&HS[0][bc][recv * 64 + brow][0] = o;
        }
    }
    __syncthreads();

    float amsg[2][2] = {{0.f, 0.f}, {0.f, 0.f}};
    f32x16 acc[4][2];

    for (int it = 0; it < 32; ++it) {
        const int kT = it >> 3, kcT = it & 7;
        if (kcT == 0) {
#pragma unroll
            for (int mt = 0; mt < 4; ++mt)
#pragma unroll
                for (int nt = 0; nt < 2; ++nt) acc[mt][nt] = (f32x16)(0.f);
        }
        // prefetch next W chunk (glds) and next S slice (regs)
        u16x8 svN;
        if (it < 31) {
            const u16* src = W2t + (size_t)(it + 1) * 8192 + w * 2048;
            u16* dst = &WtS[(it + 1) & 1][w * 2048];
#pragma unroll
            for (int it2 = 0; it2 < 4; ++it2)
                gl_lds16(src + it2 * 512 + lane * 8, dst + it2 * 512);
            const int kT2 = (it + 1) >> 3, kc2 = (it + 1) & 7;
            svN = *(const u16x8*)&S[((size_t)(kT2 * 2048 + b * 64 + brow)) * 256 + kc2 * 32 + bc * 8];
        }
        // MFMA on current H + W
        const u16* buf = WtS[it & 1];
        const u16(*hs)[128][8] = HS[it & 1];
#pragma unroll
        for (int ks2 = 0; ks2 < 2; ++ks2) {
            bf16x8 A[4], Bv[2];
#pragma unroll
            for (int mt = 0; mt < 4; ++mt)
                A[mt] = *(const bf16x8*)&hs[ks2 * 2 + lh][mt * 32 + l31][0];
#pragma unroll
            for (int nt = 0; nt < 2; ++nt)
                Bv[nt] = *(const bf16x8*)&buf[(ks2 * 2 + lh) * 2048 + (w * 64 + nt * 32 + l31) * 8];
#pragma unroll
            for (int mt = 0; mt < 4; ++mt)
#pragma unroll
                for (int nt = 0; nt < 2; ++nt)
                    acc[mt][nt] = __builtin_amdgcn_mfma_f32_32x32x16_bf16(A[mt], Bv[nt], acc[mt][nt], 0, 0, 0);
        }
        // build next H chunk
        if (it < 31) {
            const int kT2 = (it + 1) >> 3, kc2 = (it + 1) & 7;
            const int db = (it + 1) & 1;
#pragma unroll
            for (int recv = 0; recv < 2; ++recv) {
                const float* rp = &Rf[recv][kT2][kc2 * 32 + bc * 8];
                f32x4 r0 = *(const f32x4*)rp, r1 = *(const f32x4*)(rp + 4);
                bf16x8 o;
#pragma unroll
                for (int e = 0; e < 4; ++e) {
                    o[e]     = (__bf16)fmaxf(r0[e] + bf2f(svN[e]),     0.f);
                    o[4 + e] = (__bf16)fmaxf(r1[e] + bf2f(svN[4 + e]), 0.f);
                }
                *(bf16x8*)&HS[db][bc][recv * 64 + brow][0] = o;
            }
        }
        // per-k epilogue: bias + relu + rel_type-weighted row fold
        if (kcT == 7) {
#pragma unroll
            for (int nt = 0; nt < 2; ++nt) {
                const float bias = b2[kT * 256 + w * 64 + nt * 32 + l31];
#pragma unroll
                for (int mt = 0; mt < 4; ++mt) {
                    const int recv = mt >> 1;
                    float s = 0.f;
#pragma unroll
                    for (int rq = 0; rq < 4; ++rq) {
                        f32x4 rt4 = *(const f32x4*)&rtS[recv][kT][(mt & 1) * 32 + rq * 8 + 4 * lh];
#pragma unroll
                        for (int e = 0; e < 4; ++e) {
                            float v = acc[mt][nt][rq * 4 + e] + bias;
                            v = v > 0.f ? v : 0.f;
                            s += rt4[e] * v;
                        }
                    }
                    amsg[recv][nt] += s;
                }
            }
        }
        __syncthreads();
    }

    // fold lh halves; unique writer per slot
#pragma unroll
    for (int recv = 0; recv < 2; ++recv)
#pragma unroll
        for (int nt = 0; nt < 2; ++nt) {
            float s = amsg[recv][nt] + __shfl_xor(amsg[recv][nt], 32);
            if (lh == 0)
                aggb[(size_t)(b * 64 + i0 + recv) * 256 + w * 64 + nt * 32 + l31] = f2bf(s);
        }
}

// ---------------- output MLP: 64 blocks x 32 rows, LDS-staged weights ----------------
__global__ __launch_bounds__(256) void outmlp2_kernel(
    const float* __restrict__ x, const u16* __restrict__ aggb,
    const float* __restrict__ Wo1, const float* __restrict__ bo1,
    const float* __restrict__ Wo2, const float* __restrict__ bo2,
    const float* __restrict__ Wo3, const float* __restrict__ bo3,
    float* __restrict__ out)
{
    __shared__ u16 wch[4][256][8];   // cf weight chunk [g][n][8kk]
    __shared__ u16 p1S[32 * 264];
    __shared__ u16 p2S[32 * 264];
    const int tid = threadIdx.x, lane = tid & 63, w = tid >> 6;
    const int quad = lane >> 4, mloc = lane & 15;
    const int row0 = blockIdx.x * 32;

    {   // ---- L1: K=384 (12 chunks), N=256, aug=[x|agg] ----
        f32x4 acc[2][4];
#pragma unroll
        for (int mt = 0; mt < 2; ++mt)
#pragma unroll
            for (int nt = 0; nt < 4; ++nt) acc[mt][nt] = (f32x4){0.f, 0.f, 0.f, 0.f};
        for (int kk = 0; kk < 12; ++kk) {
            __syncthreads();
#pragma unroll
            for (int g = 0; g < 4; ++g) {
                u16x8 o;
#pragma unroll
                for (int e = 0; e < 8; ++e) o[e] = f2bf(Wo1[(kk * 32 + g * 8 + e) * 256 + tid]);
                *(u16x8*)&wch[g][tid][0] = o;
            }
            __syncthreads();
            bf16x8 aF[2];
#pragma unroll
            for (int mt = 0; mt < 2; ++mt) {
                const int row = row0 + mt * 16 + mloc;
                if (kk < 4) {
                    u16x8 t;
#pragma unroll
                    for (int e = 0; e < 8; ++e) t[e] = f2bf(x[row * 128 + kk * 32 + quad * 8 + e]);
                    __builtin_memcpy(&aF[mt], &t, 16);
                } else {
                    aF[mt] = *(const bf16x8*)&aggb[(size_t)row * 256 + (kk - 4) * 32 + quad * 8];
                }
            }
#pragma unroll
            for (int nt = 0; nt < 4; ++nt) {
                bf16x8 bF = *(const bf16x8*)&wch[quad][w * 64 + nt * 16 + mloc][0];
#pragma unroll
                for (int mt = 0; mt < 2; ++mt)
                    acc[mt][nt] = __builtin_amdgcn_mfma_f32_16x16x32_bf16(aF[mt], bF, acc[mt][nt], 0, 0, 0);
            }
        }
#pragma unroll
        for (int nt = 0; nt < 4; ++nt) {
            const int n = w * 64 + nt * 16 + mloc;
            const float bias = bo1[n];
#pragma unroll
            for (int mt = 0; mt < 2; ++mt)
#pragma unroll
                for (int r = 0; r < 4; ++r) {
                    float v = acc[mt][nt][r] + bias;
                    p1S[(mt * 16 + quad * 4 + r) * 264 + n] = f2bf(v > 0.f ? v : 0.f);
                }
        }
    }
    __syncthreads();
    {   // ---- L2: K=256 (8 chunks), N=256 ----
        f32x4 acc[2][4];
#pragma unroll
        for (int mt = 0; mt < 2; ++mt)
#pragma unroll
            for (int nt = 0; nt < 4; ++nt) acc[mt][nt] = (f32x4){0.f, 0.f, 0.f, 0.f};
        for (int kk = 0; kk < 8; ++kk) {
            __syncthreads();
#pragma unroll
            for (int g = 0; g < 4; ++g) {
                u16x8 o;
#pragma unroll
                for (int e = 0; e < 8; ++e) o[e] = f2bf(Wo2[(kk * 32 + g * 8 + e) * 256 + tid]);
                *(u16x8*)&wch[g][tid][0] = o;
            }
            __syncthreads();
            bf16x8 aF[2];
#pragma unroll
            for (int mt = 0; mt < 2; ++mt)
                aF[mt] = *(const bf16x8*)&p1S[(mt * 16 + mloc) * 264 + kk * 32 + quad * 8];
#pragma unroll
            for (int nt = 0; nt < 4; ++nt) {
                bf16x8 bF = *(const bf16x8*)&wch[quad][w * 64 + nt * 16 + mloc][0];
#pragma unroll
                for (int mt = 0; mt < 2; ++mt)
                    acc[mt][nt] = __builtin_amdgcn_mfma_f32_16x16x32_bf16(aF[mt], bF, acc[mt][nt], 0, 0, 0);
            }
        }
#pragma unroll
        for (int nt = 0; nt < 4; ++nt) {
            const int n = w * 64 + nt * 16 + mloc;
            const float bias = bo2[n];
#pragma unroll
            for (int mt = 0; mt < 2; ++mt)
#pragma unroll
                for (int r = 0; r < 4; ++r) {
                    float v = acc[mt][nt][r] + bias;
                    p2S[(mt * 16 + quad * 4 + r) * 264 + n] = f2bf(v > 0.f ? v : 0.f);
                }
        }
    }
    __syncthreads();
    {   // ---- L3: K=256 (8 chunks), N=128, residual ----
        f32x4 acc[2][2];
#pragma unroll
        for (int mt = 0; mt < 2; ++mt)
#pragma unroll
            for (int nt = 0; nt < 2; ++nt) acc[mt][nt] = (f32x4){0.f, 0.f, 0.f, 0.f};
        const int sn = tid & 127, sh = tid >> 7;
        for (int kk = 0; kk < 8; ++kk) {
            __syncthreads();
#pragma unroll
            for (int g2 = 0; g2 < 2; ++g2) {
                const int g = sh * 2 + g2;
                u16x8 o;
#pragma unroll
                for (int e = 0; e < 8; ++e) o[e] = f2bf(Wo3[(kk * 32 + g * 8 + e) * 128 + sn]);
                *(u16x8*)&wch[g][sn][0] = o;
            }
            __syncthreads();
            bf16x8 aF[2];
#pragma unroll
            for (int mt = 0; mt < 2; ++mt)
                aF[mt] = *(const bf16x8*)&p2S[(mt * 16 + mloc) * 264 + kk * 32 + quad * 8];
#pragma unroll
            for (int nt = 0; nt < 2; ++nt) {
                bf16x8 bF = *(const bf16x8*)&wch[quad][w * 32 + nt * 16 + mloc][0];
#pragma unroll
                for (int mt = 0; mt < 2; ++mt)
                    acc[mt][nt] = __builtin_amdgcn_mfma_f32_16x16x32_bf16(aF[mt], bF, acc[mt][nt], 0, 0, 0);
            }
        }
#pragma unroll
        for (int nt = 0; nt < 2; ++nt) {
            const int n = w * 32 + nt * 16 + mloc;
            const float bias = bo3[n];
#pragma unroll
            for (int mt = 0; mt < 2; ++mt)
#pragma unroll
                for (int r = 0; r < 4; ++r) {
                    const int grow = row0 + mt * 16 + quad * 4 + r;
                    out[grow * 128 + n] = x[grow * 128 + n] + acc[mt][nt][r] + bias;
                }
        }
    }
}

extern "C" void kernel_launch(void* const* d_in, const int* in_sizes, int n_in,
                              void* d_out, int out_size, void* d_ws, size_t ws_size,
                              hipStream_t stream) {
    const float* x   = (const float*)d_in[0];
    const float* rel = (const float*)d_in[1];
    const float* W1  = (const float*)d_in[4];
    const float* b1  = (const float*)d_in[5];
    const float* W2  = (const float*)d_in[6];
    const float* b2  = (const float*)d_in[7];
    const float* Wo1 = (const float*)d_in[8];
    const float* bo1 = (const float*)d_in[9];
    const float* Wo2 = (const float*)d_in[10];
    const float* bo2 = (const float*)d_in[11];
    const float* Wo3 = (const float*)d_in[12];
    const float* bo3 = (const float*)d_in[13];
    float* out = (float*)d_out;

    char* ws = (char*)d_ws;
    u16* W2t  = (u16*)(ws + WS_W2T);
    u16* R    = (u16*)(ws + WS_R);
    u16* S    = (u16*)(ws + WS_S);
    u16* aggb = (u16*)(ws + WS_AGG);

    prep_rs_kernel<<<1280, 256, 0, stream>>>(W2, x, W1, b1, W2t, R, S);
    edge5_kernel<<<1024, 256, 0, stream>>>(R, S, rel, W2t, b2, aggb);
    outmlp2_kernel<<<64, 256, 0, stream>>>(x, aggb, Wo1, bo1, Wo2, bo2, Wo3, bo3, out);
}